// Round 1
// baseline (1650.285 us; speedup 1.0000x reference)
//
#include <hip/hip_runtime.h>
#include <math.h>

#define DCH 384
#define NH 12
#define CH 32
#define SS 128
#define LL 256
#define NPOS 32768        // SS*LL
#define THREE_D 1152

// ---------------------------------------------------------------------------
// GEMM: Y[o][p] = sum_k W[o][k] * X[k][p] + bias[o]
// M=1152 (o), K=384, N=32768 (p). fp32 vector GEMM, 128x128 tile, 8x8/thread.
// ---------------------------------------------------------------------------
__global__ __launch_bounds__(256) void qkv_gemm(const float* __restrict__ W,
                                                const float* __restrict__ bias,
                                                const float* __restrict__ X,
                                                float* __restrict__ Y) {
    __shared__ float As[16][128];  // [k][o]
    __shared__ float Bs[16][128];  // [k][p]
    const int tid = threadIdx.x;
    const int o0 = blockIdx.y * 128;
    const int p0 = blockIdx.x * 128;
    const int tx = tid & 15, ty = tid >> 4;

    const int a_col4 = tid & 3;    // float4 index along k
    const int a_row  = tid >> 2;   // 0..63
    const int b_col4 = tid & 31;   // float4 index along p
    const int b_row  = tid >> 5;   // 0..7

    float acc[8][8] = {};

    for (int kk = 0; kk < DCH; kk += 16) {
#pragma unroll
        for (int r = 0; r < 2; ++r) {
            int o = o0 + a_row + r * 64;
            float4 a = *(const float4*)&W[(size_t)o * DCH + kk + a_col4 * 4];
            As[a_col4 * 4 + 0][a_row + r * 64] = a.x;
            As[a_col4 * 4 + 1][a_row + r * 64] = a.y;
            As[a_col4 * 4 + 2][a_row + r * 64] = a.z;
            As[a_col4 * 4 + 3][a_row + r * 64] = a.w;
        }
#pragma unroll
        for (int r = 0; r < 2; ++r) {
            int krow = b_row + r * 8;
            float4 bv = *(const float4*)&X[(size_t)(kk + krow) * NPOS + p0 + b_col4 * 4];
            *(float4*)&Bs[krow][b_col4 * 4] = bv;
        }
        __syncthreads();
#pragma unroll
        for (int k = 0; k < 16; ++k) {
            float a[8], b[8];
            *(float4*)&a[0] = *(const float4*)&As[k][ty * 8];
            *(float4*)&a[4] = *(const float4*)&As[k][ty * 8 + 4];
            *(float4*)&b[0] = *(const float4*)&Bs[k][tx * 8];
            *(float4*)&b[4] = *(const float4*)&Bs[k][tx * 8 + 4];
#pragma unroll
            for (int i = 0; i < 8; ++i)
#pragma unroll
                for (int j = 0; j < 8; ++j)
                    acc[i][j] += a[i] * b[j];
        }
        __syncthreads();
    }
#pragma unroll
    for (int i = 0; i < 8; ++i) {
        int o = o0 + ty * 8 + i;
        float bo = bias[o];
        float4 v0 = {acc[i][0] + bo, acc[i][1] + bo, acc[i][2] + bo, acc[i][3] + bo};
        float4 v1 = {acc[i][4] + bo, acc[i][5] + bo, acc[i][6] + bo, acc[i][7] + bo};
        *(float4*)&Y[(size_t)o * NPOS + p0 + tx * 8]     = v0;
        *(float4*)&Y[(size_t)o * NPOS + p0 + tx * 8 + 4] = v1;
    }
}

// ---------------------------------------------------------------------------
// Axial attention for one (head, other) slice. SEQ = attended length,
// NTHREADS == SEQ. Y holds q/k/v stacked [3*384][NPOS]; positions for this
// slice are pbase..pbase+SEQ-1 (contiguous). Writes R = X + attn_out.
// Two-pass softmax (max, then exp/accum) in fp32 — no 1/sqrt(d) scaling
// per the reference.
// ---------------------------------------------------------------------------
template <int SEQ, int NTHREADS>
__global__ __launch_bounds__(NTHREADS) void axial_attn(const float* __restrict__ Y,
                                                       const float* __restrict__ X,
                                                       float* __restrict__ R) {
    __shared__ __align__(16) float ks[SEQ][CH];  // [pos][c], b128-broadcast reads
    __shared__ __align__(16) float vs[SEQ][CH];
    const int tid = threadIdx.x;
    const int h = blockIdx.x % NH;
    const int other = blockIdx.x / NH;
    const size_t pbase = (size_t)other * SEQ;

    const float* kg = Y + ((size_t)(DCH + h * CH)) * NPOS + pbase;
    const float* vg = Y + ((size_t)(2 * DCH + h * CH)) * NPOS + pbase;
#pragma unroll
    for (int c = 0; c < CH; ++c) {
        ks[tid][c] = kg[(size_t)c * NPOS + tid];   // global read coalesced per c
        vs[tid][c] = vg[(size_t)c * NPOS + tid];
    }
    __syncthreads();

    const float* qg = Y + ((size_t)(h * CH)) * NPOS + pbase;
    float q[CH];
#pragma unroll
    for (int c = 0; c < CH; ++c) q[c] = qg[(size_t)c * NPOS + tid];

    // pass 1: row max of logits
    float m = -1e30f;
    for (int j = 0; j < SEQ; ++j) {
        const float4* k4 = (const float4*)&ks[j][0];
        float dot = 0.f;
#pragma unroll
        for (int c4 = 0; c4 < 8; ++c4) {
            float4 kv = k4[c4];
            dot += q[c4 * 4 + 0] * kv.x + q[c4 * 4 + 1] * kv.y +
                   q[c4 * 4 + 2] * kv.z + q[c4 * 4 + 3] * kv.w;
        }
        m = fmaxf(m, dot);
    }

    // pass 2: softmax-weighted accumulation over v
    float lsum = 0.f;
    float acc[CH] = {};
    for (int j = 0; j < SEQ; ++j) {
        const float4* k4 = (const float4*)&ks[j][0];
        float dot = 0.f;
#pragma unroll
        for (int c4 = 0; c4 < 8; ++c4) {
            float4 kv = k4[c4];
            dot += q[c4 * 4 + 0] * kv.x + q[c4 * 4 + 1] * kv.y +
                   q[c4 * 4 + 2] * kv.z + q[c4 * 4 + 3] * kv.w;
        }
        float w = __expf(dot - m);
        lsum += w;
        const float4* v4 = (const float4*)&vs[j][0];
#pragma unroll
        for (int c4 = 0; c4 < 8; ++c4) {
            float4 vv = v4[c4];
            acc[c4 * 4 + 0] += w * vv.x;
            acc[c4 * 4 + 1] += w * vv.y;
            acc[c4 * 4 + 2] += w * vv.z;
            acc[c4 * 4 + 3] += w * vv.w;
        }
    }
    float inv = 1.f / lsum;

    const float* xg = X + ((size_t)(h * CH)) * NPOS + pbase;
    float* rg = R + ((size_t)(h * CH)) * NPOS + pbase;
#pragma unroll
    for (int c = 0; c < CH; ++c)
        rg[(size_t)c * NPOS + tid] = xg[(size_t)c * NPOS + tid] + acc[c] * inv;
}

// ---------------------------------------------------------------------------
// Channel LayerNorm in place: A[d][p], normalize over d=0..383 per position p.
// ---------------------------------------------------------------------------
__global__ __launch_bounds__(256) void chan_ln(float* __restrict__ A,
                                               const float* __restrict__ w,
                                               const float* __restrict__ b) {
    const int p = blockIdx.x * 256 + threadIdx.x;
    float sum = 0.f, sq = 0.f;
    for (int d = 0; d < DCH; ++d) {
        float v = A[(size_t)d * NPOS + p];
        sum += v;
        sq += v * v;
    }
    const float mean = sum * (1.f / DCH);
    float var = sq * (1.f / DCH) - mean * mean;
    const float rstd = rsqrtf(var + 1e-5f);
    for (int d = 0; d < DCH; ++d) {
        float v = A[(size_t)d * NPOS + p];
        A[(size_t)d * NPOS + p] = (v - mean) * rstd * w[d] + b[d];
    }
}

// ---------------------------------------------------------------------------
// Per-channel 2D transpose: in [DCH][Rr][Cc] -> out [DCH][Cc][Rr]
// ---------------------------------------------------------------------------
__global__ __launch_bounds__(256) void transpose_dp(const float* __restrict__ in,
                                                    float* __restrict__ out,
                                                    int Rr, int Cc) {
    __shared__ float tile[32][33];
    const int ntc = Cc >> 5, ntr = Rr >> 5;
    int tc = blockIdx.x % ntc;
    int tr = (blockIdx.x / ntc) % ntr;
    int d = blockIdx.x / (ntc * ntr);
    int tx = threadIdx.x & 31, ty = threadIdx.x >> 5;  // ty 0..7
    const float* ip = in + (size_t)d * Rr * Cc;
    float* op = out + (size_t)d * Rr * Cc;
#pragma unroll
    for (int i = 0; i < 32; i += 8)
        tile[ty + i][tx] = ip[(size_t)(tr * 32 + ty + i) * Cc + tc * 32 + tx];
    __syncthreads();
#pragma unroll
    for (int i = 0; i < 32; i += 8)
        op[(size_t)(tc * 32 + ty + i) * Rr + tr * 32 + tx] = tile[tx][ty + i];
}

extern "C" void kernel_launch(void* const* d_in, const int* in_sizes, int n_in,
                              void* d_out, int out_size, void* d_ws, size_t ws_size,
                              hipStream_t stream) {
    const float* x     = (const float*)d_in[0];
    const float* row_w = (const float*)d_in[1];
    const float* row_b = (const float*)d_in[2];
    const float* col_w = (const float*)d_in[3];
    const float* col_b = (const float*)d_in[4];
    const float* ln1_w = (const float*)d_in[5];
    const float* ln1_b = (const float*)d_in[6];
    const float* ln2_w = (const float*)d_in[7];
    const float* ln2_b = (const float*)d_in[8];
    float* out = (float*)d_out;

    char* ws = (char*)d_ws;
    const size_t ybytes = (size_t)THREE_D * NPOS * 4;  // 151 MB
    const size_t abytes = (size_t)DCH * NPOS * 4;      // 50.3 MB
    float* Y = (float*)ws;                   // qkv output (reused for stage 2)
    float* A = (float*)(ws + ybytes);        // residual / LN buffer
    float* T = (float*)(ws + ybytes + abytes);  // transposed out1

    dim3 gemm_grid(NPOS / 128, THREE_D / 128);

    // ---- stage 1: row attention (attend over L within each row s) ----
    qkv_gemm<<<gemm_grid, 256, 0, stream>>>(row_w, row_b, x, Y);
    axial_attn<LL, LL><<<NH * SS, LL, 0, stream>>>(Y, x, A);   // A = x + row_out
    chan_ln<<<NPOS / 256, 256, 0, stream>>>(A, ln1_w, ln1_b);  // A = out1
    // transpose out1 [d][s][l] -> [d][l][s] for coalesced column attention
    transpose_dp<<<DCH * (SS / 32) * (LL / 32), 256, 0, stream>>>(A, T, SS, LL);

    // ---- stage 2: column attention (attend over S within each column l) ----
    qkv_gemm<<<gemm_grid, 256, 0, stream>>>(col_w, col_b, T, Y);
    axial_attn<SS, SS><<<NH * LL, SS, 0, stream>>>(Y, T, A);   // A = out1 + col_out (transposed)
    chan_ln<<<NPOS / 256, 256, 0, stream>>>(A, ln2_w, ln2_b);  // A = out2 (transposed)
    // transpose back [d][l][s] -> [d][s][l] into d_out
    transpose_dp<<<DCH * (LL / 32) * (SS / 32), 256, 0, stream>>>(A, out, LL, SS);
}

// Round 3
// 888.286 us; speedup vs baseline: 1.8578x; 1.8578x over previous
//
#include <hip/hip_runtime.h>
#include <math.h>

#define DCH 384
#define NH 12
#define CH 32
#define SS 128
#define LL 256
#define NPOS 32768        // SS*LL
#define THREE_D 1152

typedef _Float16 f16_t;
typedef _Float16 f16x8 __attribute__((ext_vector_type(8)));
typedef float f32x4 __attribute__((ext_vector_type(4)));

// async global->LDS, 16B per lane; LDS dest = base + lane*16 (wave-uniform base)
#define GLD16(gptr, lptr) __builtin_amdgcn_global_load_lds( \
    (const __attribute__((address_space(1))) unsigned int*)(gptr), \
    (__attribute__((address_space(3))) unsigned int*)(lptr), 16, 0, 0)

// ---------------------------------------------------------------------------
// fp32 -> fp16 elementwise (weights, layout preserved). n4 = count/4.
// ---------------------------------------------------------------------------
__global__ __launch_bounds__(256) void conv_w(const float* __restrict__ in,
                                              f16_t* __restrict__ out, int n4) {
    int i = blockIdx.x * 256 + threadIdx.x;
    if (i < n4) {
        float4 v = ((const float4*)in)[i];
        unsigned short u0 = __builtin_bit_cast(unsigned short, (f16_t)v.x);
        unsigned short u1 = __builtin_bit_cast(unsigned short, (f16_t)v.y);
        unsigned short u2 = __builtin_bit_cast(unsigned short, (f16_t)v.z);
        unsigned short u3 = __builtin_bit_cast(unsigned short, (f16_t)v.w);
        uint2 r;
        r.x = (unsigned)u0 | ((unsigned)u1 << 16);
        r.y = (unsigned)u2 | ((unsigned)u3 << 16);
        ((uint2*)out)[i] = r;
    }
}

// ---------------------------------------------------------------------------
// fp32 [DCH][NPOS] -> fp16 [NPOS][DCH]  (transpose + convert, 64x64 tiles)
// ---------------------------------------------------------------------------
__global__ __launch_bounds__(256) void conv_xT(const float* __restrict__ in,
                                               f16_t* __restrict__ outp) {
    __shared__ float tile[64][65];
    const int p0 = blockIdx.x * 64;
    const int k0 = blockIdx.y * 64;
    const int tx = threadIdx.x & 63, ty = threadIdx.x >> 6;  // ty 0..3
#pragma unroll
    for (int i = 0; i < 16; ++i)
        tile[ty * 16 + i][tx] = in[(size_t)(k0 + ty * 16 + i) * NPOS + p0 + tx];
    __syncthreads();
    const int pr = threadIdx.x >> 2;   // 0..63 output row (p)
    const int cg = threadIdx.x & 3;    // 16-col group (k)
    union { uint4 v[2]; unsigned int u[8]; } res;
#pragma unroll
    for (int j = 0; j < 8; ++j) {
        unsigned short lo = __builtin_bit_cast(unsigned short, (f16_t)tile[cg * 16 + 2 * j][pr]);
        unsigned short hi = __builtin_bit_cast(unsigned short, (f16_t)tile[cg * 16 + 2 * j + 1][pr]);
        res.u[j] = (unsigned)lo | ((unsigned)hi << 16);
    }
    uint4* dst = (uint4*)&outp[(size_t)(p0 + pr) * DCH + k0 + cg * 16];
    dst[0] = res.v[0];
    dst[1] = res.v[1];
}

// ---------------------------------------------------------------------------
// fp16 MFMA GEMM: Y[o][p] = sum_k Wh[o][k] * Xp[p][k] + bias[o]
// M=1152, K=384, N=32768. 128x128 tile, 4 waves in 2x2, each wave 64x64 via
// 4x4 of 16x16x32 MFMA. global_load_lds width-16 staging (m97 pattern).
// ---------------------------------------------------------------------------
__global__ __launch_bounds__(256) void qkv_gemm_f16(
        const f16_t* __restrict__ Wh,    // [THREE_D][DCH]
        const float* __restrict__ bias,  // [THREE_D]
        const f16_t* __restrict__ Xp,    // [NPOS][DCH]
        float* __restrict__ Y)           // [THREE_D][NPOS]
{
    __shared__ f16_t sha[128 * 32];  // [o_local][k] row-major, 8 KB
    __shared__ f16_t shb[128 * 32];  // [p_local][k] row-major, 8 KB
    const int tid  = threadIdx.x;
    const int lane = tid & 63;
    const int wave = tid >> 6;
    const int o0 = blockIdx.y * 128;
    const int p0 = blockIdx.x * 128;
    const int wr = wave >> 1, wc = wave & 1;   // 2x2 wave grid

    f32x4 acc[4][4] = {};

    // staging: chunk c covers LDS elems [c*8, c*8+8) == row c>>2, kgroup c&3.
    // wave handles chunks [wave*128, wave*128+128) via two 64-lane loads.
    const int c0 = wave * 128 + lane;
    const int c1 = c0 + 64;
    const f16_t* ga0 = Wh + (size_t)(o0 + (c0 >> 2)) * DCH + (c0 & 3) * 8;
    const f16_t* ga1 = Wh + (size_t)(o0 + (c1 >> 2)) * DCH + (c1 & 3) * 8;
    const f16_t* gb0 = Xp + (size_t)(p0 + (c0 >> 2)) * DCH + (c0 & 3) * 8;
    const f16_t* gb1 = Xp + (size_t)(p0 + (c1 >> 2)) * DCH + (c1 & 3) * 8;
    f16_t* la0 = sha + (wave * 128) * 8;
    f16_t* la1 = sha + (wave * 128 + 64) * 8;
    f16_t* lb0 = shb + (wave * 128) * 8;
    f16_t* lb1 = shb + (wave * 128 + 64) * 8;

    const int mrow = lane & 15;          // m (or n) within 16-tile
    const int kg8  = (lane >> 4) * 8;    // k-subgroup of 8

    for (int kk = 0; kk < DCH; kk += 32) {
        GLD16(ga0 + kk, la0);
        GLD16(ga1 + kk, la1);
        GLD16(gb0 + kk, lb0);
        GLD16(gb1 + kk, lb1);
        __syncthreads();   // drains vmcnt -> LDS visible
        f16x8 af[4], bfr[4];
#pragma unroll
        for (int mi = 0; mi < 4; ++mi)
            af[mi] = *(const f16x8*)(sha + (wr * 64 + mi * 16 + mrow) * 32 + kg8);
#pragma unroll
        for (int ni = 0; ni < 4; ++ni)
            bfr[ni] = *(const f16x8*)(shb + (wc * 64 + ni * 16 + mrow) * 32 + kg8);
#pragma unroll
        for (int mi = 0; mi < 4; ++mi)
#pragma unroll
            for (int ni = 0; ni < 4; ++ni)
                acc[mi][ni] = __builtin_amdgcn_mfma_f32_16x16x32_f16(
                    af[mi], bfr[ni], acc[mi][ni], 0, 0, 0);
        __syncthreads();   // all waves done reading before next stage overwrites
    }

    // C/D layout: col = lane&15, row = (lane>>4)*4 + r (dtype-independent, m89/m121)
    const int col = lane & 15;
    const int rq4 = (lane >> 4) * 4;
#pragma unroll
    for (int mi = 0; mi < 4; ++mi) {
        int obase = o0 + wr * 64 + mi * 16 + rq4;
#pragma unroll
        for (int r = 0; r < 4; ++r) {
            float bo = bias[obase + r];
            size_t yb = (size_t)(obase + r) * NPOS + p0 + wc * 64 + col;
#pragma unroll
            for (int ni = 0; ni < 4; ++ni)
                Y[yb + ni * 16] = acc[mi][ni][r] + bo;
        }
    }
}

// ---------------------------------------------------------------------------
// Axial attention, single-pass softmax WITHOUT max subtraction (fp32 range
// analysis: logit max ~34 -> exp ~6e14, sum <= 1.5e17 << 3.4e38).
// ---------------------------------------------------------------------------
template <int SEQ>
__global__ __launch_bounds__(SEQ) void axial_attn(const float* __restrict__ Y,
                                                  const float* __restrict__ X,
                                                  float* __restrict__ R) {
    __shared__ __align__(16) float ks[SEQ][CH];
    __shared__ __align__(16) float vs[SEQ][CH];
    const int tid = threadIdx.x;
    const int h = blockIdx.x % NH;
    const int other = blockIdx.x / NH;
    const size_t pbase = (size_t)other * SEQ;

    const float* kg = Y + ((size_t)(DCH + h * CH)) * NPOS + pbase;
    const float* vg = Y + ((size_t)(2 * DCH + h * CH)) * NPOS + pbase;
#pragma unroll
    for (int c = 0; c < CH; ++c) {
        ks[tid][c] = kg[(size_t)c * NPOS + tid];
        vs[tid][c] = vg[(size_t)c * NPOS + tid];
    }
    __syncthreads();

    const float* qg = Y + ((size_t)(h * CH)) * NPOS + pbase;
    float q[CH];
#pragma unroll
    for (int c = 0; c < CH; ++c) q[c] = qg[(size_t)c * NPOS + tid];

    float lsum = 0.f;
    float acc[CH] = {};
    for (int j = 0; j < SEQ; ++j) {
        const float4* k4 = (const float4*)&ks[j][0];
        float dot = 0.f;
#pragma unroll
        for (int c4 = 0; c4 < 8; ++c4) {
            float4 kv = k4[c4];
            dot += q[c4 * 4 + 0] * kv.x + q[c4 * 4 + 1] * kv.y +
                   q[c4 * 4 + 2] * kv.z + q[c4 * 4 + 3] * kv.w;
        }
        float w = __expf(dot);
        lsum += w;
        const float4* v4 = (const float4*)&vs[j][0];
#pragma unroll
        for (int c4 = 0; c4 < 8; ++c4) {
            float4 vv = v4[c4];
            acc[c4 * 4 + 0] += w * vv.x;
            acc[c4 * 4 + 1] += w * vv.y;
            acc[c4 * 4 + 2] += w * vv.z;
            acc[c4 * 4 + 3] += w * vv.w;
        }
    }
    float inv = 1.f / lsum;

    const float* xg = X + ((size_t)(h * CH)) * NPOS + pbase;
    float* rg = R + ((size_t)(h * CH)) * NPOS + pbase;
#pragma unroll
    for (int c = 0; c < CH; ++c)
        rg[(size_t)c * NPOS + tid] = xg[(size_t)c * NPOS + tid] + acc[c] * inv;
}

// ---------------------------------------------------------------------------
// Channel LayerNorm in place: A[d][p], normalize over d per position p.
// ---------------------------------------------------------------------------
__global__ __launch_bounds__(256) void chan_ln(float* __restrict__ A,
                                               const float* __restrict__ w,
                                               const float* __restrict__ b) {
    const int p = blockIdx.x * 256 + threadIdx.x;
    float sum = 0.f, sq = 0.f;
    for (int d = 0; d < DCH; ++d) {
        float v = A[(size_t)d * NPOS + p];
        sum += v;
        sq += v * v;
    }
    const float mean = sum * (1.f / DCH);
    float var = sq * (1.f / DCH) - mean * mean;
    const float rstd = rsqrtf(var + 1e-5f);
    for (int d = 0; d < DCH; ++d) {
        float v = A[(size_t)d * NPOS + p];
        A[(size_t)d * NPOS + p] = (v - mean) * rstd * w[d] + b[d];
    }
}

// ---------------------------------------------------------------------------
// Per-channel 2D transpose: in [DCH][Rr][Cc] -> out [DCH][Cc][Rr]
// ---------------------------------------------------------------------------
__global__ __launch_bounds__(256) void transpose_dp(const float* __restrict__ in,
                                                    float* __restrict__ out,
                                                    int Rr, int Cc) {
    __shared__ float tile[32][33];
    const int ntc = Cc >> 5, ntr = Rr >> 5;
    int tc = blockIdx.x % ntc;
    int tr = (blockIdx.x / ntc) % ntr;
    int d = blockIdx.x / (ntc * ntr);
    int tx = threadIdx.x & 31, ty = threadIdx.x >> 5;  // ty 0..7
    const float* ip = in + (size_t)d * Rr * Cc;
    float* op = out + (size_t)d * Rr * Cc;
#pragma unroll
    for (int i = 0; i < 32; i += 8)
        tile[ty + i][tx] = ip[(size_t)(tr * 32 + ty + i) * Cc + tc * 32 + tx];
    __syncthreads();
#pragma unroll
    for (int i = 0; i < 32; i += 8)
        op[(size_t)(tc * 32 + ty + i) * Rr + tr * 32 + tx] = tile[tx][ty + i];
}

extern "C" void kernel_launch(void* const* d_in, const int* in_sizes, int n_in,
                              void* d_out, int out_size, void* d_ws, size_t ws_size,
                              hipStream_t stream) {
    const float* x     = (const float*)d_in[0];
    const float* row_w = (const float*)d_in[1];
    const float* row_b = (const float*)d_in[2];
    const float* col_w = (const float*)d_in[3];
    const float* col_b = (const float*)d_in[4];
    const float* ln1_w = (const float*)d_in[5];
    const float* ln1_b = (const float*)d_in[6];
    const float* ln2_w = (const float*)d_in[7];
    const float* ln2_b = (const float*)d_in[8];
    float* out = (float*)d_out;

    char* ws = (char*)d_ws;
    const size_t ybytes = (size_t)THREE_D * NPOS * 4;  // 151.0 MB
    const size_t abytes = (size_t)DCH * NPOS * 4;      // 50.3 MB
    float* Y = (float*)ws;                      // qkv output
    float* A = (float*)(ws + ybytes);           // residual / LN buffer
    float* T = (float*)(ws + ybytes + abytes);  // transposed out1
    // fp16 scratch lives inside A's region; both are dead before axial_attn
    // overwrites A (stream-ordered). Xp: 25.2 MB at A+0; Wh: 0.9 MB at A+32MiB.
    f16_t* Xp = (f16_t*)A;
    f16_t* Wh = (f16_t*)(ws + ybytes + 33554432);

    dim3 ggrid(NPOS / 128, THREE_D / 128);
    const int wn4 = THREE_D * DCH / 4;
    dim3 cgrid(NPOS / 64, DCH / 64);

    // ---- stage 1: row attention (attend over L within each row s) ----
    conv_w<<<(wn4 + 255) / 256, 256, 0, stream>>>(row_w, Wh, wn4);
    conv_xT<<<cgrid, 256, 0, stream>>>(x, Xp);
    qkv_gemm_f16<<<ggrid, 256, 0, stream>>>(Wh, row_b, Xp, Y);
    axial_attn<LL><<<NH * SS, LL, 0, stream>>>(Y, x, A);       // A = x + row_out
    chan_ln<<<NPOS / 256, 256, 0, stream>>>(A, ln1_w, ln1_b);  // A = out1
    transpose_dp<<<DCH * (SS / 32) * (LL / 32), 256, 0, stream>>>(A, T, SS, LL);

    // ---- stage 2: column attention (attend over S within each column l) ----
    conv_w<<<(wn4 + 255) / 256, 256, 0, stream>>>(col_w, Wh, wn4);
    conv_xT<<<cgrid, 256, 0, stream>>>(T, Xp);
    qkv_gemm_f16<<<ggrid, 256, 0, stream>>>(Wh, col_b, Xp, Y);
    axial_attn<SS><<<NH * LL, SS, 0, stream>>>(Y, T, A);       // A = out1 + col_out (transposed)
    chan_ln<<<NPOS / 256, 256, 0, stream>>>(A, ln2_w, ln2_b);  // A = out2 (transposed)
    transpose_dp<<<DCH * (LL / 32) * (SS / 32), 256, 0, stream>>>(A, out, LL, SS);
}

// Round 4
// 529.483 us; speedup vs baseline: 3.1168x; 1.6776x over previous
//
#include <hip/hip_runtime.h>
#include <math.h>

#define DCH 384
#define NH 12
#define CH 32
#define SS 128
#define LL 256
#define NPOS 32768        // SS*LL
#define THREE_D 1152

typedef _Float16 f16_t;
typedef _Float16 f16x8 __attribute__((ext_vector_type(8)));
typedef float f32x4 __attribute__((ext_vector_type(4)));

// async global->LDS, 16B per lane; LDS dest = base + lane*16 (wave-uniform base)
#define GLD16(gptr, lptr) __builtin_amdgcn_global_load_lds( \
    (const __attribute__((address_space(1))) unsigned int*)(gptr), \
    (__attribute__((address_space(3))) unsigned int*)(lptr), 16, 0, 0)

// ---------------------------------------------------------------------------
// fp32 -> fp16 elementwise (weights, layout preserved). n4 = count/4.
// ---------------------------------------------------------------------------
__global__ __launch_bounds__(256) void conv_w(const float* __restrict__ in,
                                              f16_t* __restrict__ out, int n4) {
    int i = blockIdx.x * 256 + threadIdx.x;
    if (i < n4) {
        float4 v = ((const float4*)in)[i];
        unsigned short u0 = __builtin_bit_cast(unsigned short, (f16_t)v.x);
        unsigned short u1 = __builtin_bit_cast(unsigned short, (f16_t)v.y);
        unsigned short u2 = __builtin_bit_cast(unsigned short, (f16_t)v.z);
        unsigned short u3 = __builtin_bit_cast(unsigned short, (f16_t)v.w);
        uint2 r;
        r.x = (unsigned)u0 | ((unsigned)u1 << 16);
        r.y = (unsigned)u2 | ((unsigned)u3 << 16);
        ((uint2*)out)[i] = r;
    }
}

// ---------------------------------------------------------------------------
// fp32 [DCH][NPOS] -> fp16 [NPOS][DCH]  (transpose + convert, 64x64 tiles)
// ---------------------------------------------------------------------------
__global__ __launch_bounds__(256) void conv_xT(const float* __restrict__ in,
                                               f16_t* __restrict__ outp) {
    __shared__ float tile[64][65];
    const int p0 = blockIdx.x * 64;
    const int k0 = blockIdx.y * 64;
    const int tx = threadIdx.x & 63, ty = threadIdx.x >> 6;  // ty 0..3
#pragma unroll
    for (int i = 0; i < 16; ++i)
        tile[ty * 16 + i][tx] = in[(size_t)(k0 + ty * 16 + i) * NPOS + p0 + tx];
    __syncthreads();
    const int pr = threadIdx.x >> 2;   // 0..63 output row (p)
    const int cg = threadIdx.x & 3;    // 16-col group (k)
    union { uint4 v[2]; unsigned int u[8]; } res;
#pragma unroll
    for (int j = 0; j < 8; ++j) {
        unsigned short lo = __builtin_bit_cast(unsigned short, (f16_t)tile[cg * 16 + 2 * j][pr]);
        unsigned short hi = __builtin_bit_cast(unsigned short, (f16_t)tile[cg * 16 + 2 * j + 1][pr]);
        res.u[j] = (unsigned)lo | ((unsigned)hi << 16);
    }
    uint4* dst = (uint4*)&outp[(size_t)(p0 + pr) * DCH + k0 + cg * 16];
    dst[0] = res.v[0];
    dst[1] = res.v[1];
}

// ---------------------------------------------------------------------------
// fp16 MFMA GEMM producing attention-friendly fp16 outputs:
//   q,k -> Yq/Yk [NH][NPOS][CH]   (p-major rows of 32 ch: direct MFMA frags)
//   v   -> Yv [DCH][NPOS]         (c-major: V^T A-frag rows)
// o-tiles never straddle q/k/v boundaries (384 % 128 == 0).
// Grid: x = o-tile (9), y = p-tile (256) so the 9 o-tiles sharing an Xp tile
// are dispatch-adjacent (L2 reuse).
// ---------------------------------------------------------------------------
__global__ __launch_bounds__(256) void qkv_gemm_f16(
        const f16_t* __restrict__ Wh,    // [THREE_D][DCH]
        const float* __restrict__ bias,  // [THREE_D]
        const f16_t* __restrict__ Xp,    // [NPOS][DCH]
        f16_t* __restrict__ Yq, f16_t* __restrict__ Yk, f16_t* __restrict__ Yv)
{
    __shared__ f16_t sha[128 * 32];  // [o_local][k] row-major, 8 KB
    __shared__ f16_t shb[128 * 32];  // [p_local][k] row-major, 8 KB
    const int tid  = threadIdx.x;
    const int lane = tid & 63;
    const int wave = tid >> 6;
    const int ot   = blockIdx.x;       // 0..8
    const int o0 = ot * 128;
    const int p0 = blockIdx.y * 128;
    const int wr = wave >> 1, wc = wave & 1;   // 2x2 wave grid

    f32x4 acc[4][4] = {};

    const int c0 = wave * 128 + lane;
    const int c1 = c0 + 64;
    const f16_t* ga0 = Wh + (size_t)(o0 + (c0 >> 2)) * DCH + (c0 & 3) * 8;
    const f16_t* ga1 = Wh + (size_t)(o0 + (c1 >> 2)) * DCH + (c1 & 3) * 8;
    const f16_t* gb0 = Xp + (size_t)(p0 + (c0 >> 2)) * DCH + (c0 & 3) * 8;
    const f16_t* gb1 = Xp + (size_t)(p0 + (c1 >> 2)) * DCH + (c1 & 3) * 8;
    f16_t* la0 = sha + (wave * 128) * 8;
    f16_t* la1 = sha + (wave * 128 + 64) * 8;
    f16_t* lb0 = shb + (wave * 128) * 8;
    f16_t* lb1 = shb + (wave * 128 + 64) * 8;

    const int mrow = lane & 15;
    const int kg8  = (lane >> 4) * 8;

    for (int kk = 0; kk < DCH; kk += 32) {
        GLD16(ga0 + kk, la0);
        GLD16(ga1 + kk, la1);
        GLD16(gb0 + kk, lb0);
        GLD16(gb1 + kk, lb1);
        __syncthreads();
        f16x8 af[4], bfr[4];
#pragma unroll
        for (int mi = 0; mi < 4; ++mi)
            af[mi] = *(const f16x8*)(sha + (wr * 64 + mi * 16 + mrow) * 32 + kg8);
#pragma unroll
        for (int ni = 0; ni < 4; ++ni)
            bfr[ni] = *(const f16x8*)(shb + (wc * 64 + ni * 16 + mrow) * 32 + kg8);
#pragma unroll
        for (int mi = 0; mi < 4; ++mi)
#pragma unroll
            for (int ni = 0; ni < 4; ++ni)
                acc[mi][ni] = __builtin_amdgcn_mfma_f32_16x16x32_f16(
                    af[mi], bfr[ni], acc[mi][ni], 0, 0, 0);
        __syncthreads();
    }

    // C/D layout: col = lane&15 (p), row = (lane>>4)*4 + r (o)
    const int col = lane & 15;
    const int rq4 = (lane >> 4) * 4;
    const int qkv = ot / 3;     // 0=q 1=k 2=v
    const int grp = ot % 3;     // 128-block within the qkv group

    if (qkv < 2) {
        f16_t* Yt = (qkv == 0) ? Yq : Yk;
#pragma unroll
        for (int mi = 0; mi < 4; ++mi) {
            const int h  = grp * 4 + wr * 2 + (mi >> 1);
            const int cb = (mi & 1) * 16 + rq4;               // c base; +r consecutive
            const int ob = o0 + wr * 64 + mi * 16 + rq4;      // bias base
            const float b0 = bias[ob], b1 = bias[ob + 1];
            const float b2 = bias[ob + 2], b3 = bias[ob + 3];
#pragma unroll
            for (int ni = 0; ni < 4; ++ni) {
                const int p = p0 + wc * 64 + ni * 16 + col;
                union { uint2 u; f16_t h4[4]; } w;
                w.h4[0] = (f16_t)(acc[mi][ni][0] + b0);
                w.h4[1] = (f16_t)(acc[mi][ni][1] + b1);
                w.h4[2] = (f16_t)(acc[mi][ni][2] + b2);
                w.h4[3] = (f16_t)(acc[mi][ni][3] + b3);
                *(uint2*)(Yt + ((size_t)h * NPOS + p) * CH + cb) = w.u;
            }
        }
    } else {
#pragma unroll
        for (int mi = 0; mi < 4; ++mi) {
#pragma unroll
            for (int r = 0; r < 4; ++r) {
                const int cg = grp * 128 + wr * 64 + mi * 16 + rq4 + r;  // 0..383
                const float br = bias[768 + cg];
#pragma unroll
                for (int ni = 0; ni < 4; ++ni) {
                    const int p = p0 + wc * 64 + ni * 16 + col;
                    Yv[(size_t)cg * NPOS + p] = (f16_t)(acc[mi][ni][r] + br);
                }
            }
        }
    }
}

// ---------------------------------------------------------------------------
// MFMA axial attention. One block per (h, other) slice; 4 waves; wave handles
// SEQ/64 i-tiles of 16 Q-rows.
//   S^T = K * Q^T   (A=K frag, B=Q frag; C cols = i, rows = j-quads)
//   softmax over j: in-lane sum of 64/32 values + shfl-xor(16,32)
//   normalize -> fp16 P, per-wave LDS round-trip to B-frag layout
//   O^T = V^T * P^T (A=V^T from Yv, B=P; C cols = i, rows = c-quads)
//   R = X + O
// No max subtraction: logits <= ~40 -> exp < 1e18 fits fp32; P<=1 fits fp16.
// ---------------------------------------------------------------------------
template <int SEQ>
__global__ __launch_bounds__(256) void mfma_attn(
        const f16_t* __restrict__ Yq, const f16_t* __restrict__ Yk,
        const f16_t* __restrict__ Yv, const float* __restrict__ X,
        float* __restrict__ R)
{
    constexpr int JT  = SEQ / 16;    // j-tiles
    constexpr int NIT = SEQ / 64;    // i-tiles per wave
    constexpr int PST = SEQ + 8;     // padded P row stride (fp16 units)
    __shared__ f16_t pb[4][16 * PST];
    const int lane = threadIdx.x & 63;
    const int wave = threadIdx.x >> 6;
    const int col = lane & 15, quad = lane >> 4;
    const int h = blockIdx.x % NH;
    const size_t pbase = (size_t)(blockIdx.x / NH) * SEQ;

    const f16_t* qg = Yq + ((size_t)h * NPOS + pbase) * CH;
    const f16_t* kg = Yk + ((size_t)h * NPOS + pbase) * CH;
    const f16_t* vg = Yv + (size_t)h * CH * NPOS + pbase;
    f16_t* mypb = pb[wave];

    for (int it = 0; it < NIT; ++it) {
        const int i0 = (wave * NIT + it) * 16;
        const f16x8 qf = *(const f16x8*)(qg + (size_t)(i0 + col) * CH + quad * 8);
        f32x4 st[JT];
#pragma unroll
        for (int mt = 0; mt < JT; ++mt) {
            f16x8 kf = *(const f16x8*)(kg + (size_t)(mt * 16 + col) * CH + quad * 8);
            st[mt] = __builtin_amdgcn_mfma_f32_16x16x32_f16(kf, qf, (f32x4){0.f, 0.f, 0.f, 0.f}, 0, 0, 0);
        }
        float sum = 0.f;
#pragma unroll
        for (int mt = 0; mt < JT; ++mt)
#pragma unroll
            for (int r = 0; r < 4; ++r) {
                st[mt][r] = __expf(st[mt][r]);
                sum += st[mt][r];
            }
        sum += __shfl_xor(sum, 16, 64);
        sum += __shfl_xor(sum, 32, 64);
        const float inv = 1.f / sum;
#pragma unroll
        for (int mt = 0; mt < JT; ++mt) {
            union { uint2 u; f16_t h4[4]; } w;
            w.h4[0] = (f16_t)(st[mt][0] * inv);
            w.h4[1] = (f16_t)(st[mt][1] * inv);
            w.h4[2] = (f16_t)(st[mt][2] * inv);
            w.h4[3] = (f16_t)(st[mt][3] * inv);
            *(uint2*)(mypb + col * PST + mt * 16 + quad * 4) = w.u;
        }
        __syncthreads();   // drain LDS writes (cross-lane read next)

        f32x4 ot0 = {0.f, 0.f, 0.f, 0.f}, ot1 = {0.f, 0.f, 0.f, 0.f};
#pragma unroll
        for (int ks = 0; ks < SEQ / 32; ++ks) {
            f16x8 pf = *(const f16x8*)(mypb + col * PST + ks * 32 + quad * 8);
            f16x8 v0 = *(const f16x8*)(vg + (size_t)col * NPOS + ks * 32 + quad * 8);
            f16x8 v1 = *(const f16x8*)(vg + (size_t)(16 + col) * NPOS + ks * 32 + quad * 8);
            ot0 = __builtin_amdgcn_mfma_f32_16x16x32_f16(v0, pf, ot0, 0, 0, 0);
            ot1 = __builtin_amdgcn_mfma_f32_16x16x32_f16(v1, pf, ot1, 0, 0, 0);
        }
        const size_t pos = pbase + i0 + col;
#pragma unroll
        for (int r = 0; r < 4; ++r) {
            const size_t c0r = (size_t)(h * CH + quad * 4 + r) * NPOS + pos;
            const size_t c1r = (size_t)(h * CH + 16 + quad * 4 + r) * NPOS + pos;
            R[c0r] = X[c0r] + ot0[r];
            R[c1r] = X[c1r] + ot1[r];
        }
        __syncthreads();   // keep waves in step before pb reuse
    }
}

// ---------------------------------------------------------------------------
// Channel LayerNorm in place: A[d][p], normalize over d per position p.
// ---------------------------------------------------------------------------
__global__ __launch_bounds__(256) void chan_ln(float* __restrict__ A,
                                               const float* __restrict__ w,
                                               const float* __restrict__ b) {
    const int p = blockIdx.x * 256 + threadIdx.x;
    float sum = 0.f, sq = 0.f;
    for (int d = 0; d < DCH; ++d) {
        float v = A[(size_t)d * NPOS + p];
        sum += v;
        sq += v * v;
    }
    const float mean = sum * (1.f / DCH);
    float var = sq * (1.f / DCH) - mean * mean;
    const float rstd = rsqrtf(var + 1e-5f);
    for (int d = 0; d < DCH; ++d) {
        float v = A[(size_t)d * NPOS + p];
        A[(size_t)d * NPOS + p] = (v - mean) * rstd * w[d] + b[d];
    }
}

// ---------------------------------------------------------------------------
// Per-channel 2D transpose: in [DCH][Rr][Cc] -> out [DCH][Cc][Rr]
// ---------------------------------------------------------------------------
__global__ __launch_bounds__(256) void transpose_dp(const float* __restrict__ in,
                                                    float* __restrict__ out,
                                                    int Rr, int Cc) {
    __shared__ float tile[32][33];
    const int ntc = Cc >> 5, ntr = Rr >> 5;
    int tc = blockIdx.x % ntc;
    int tr = (blockIdx.x / ntc) % ntr;
    int d = blockIdx.x / (ntc * ntr);
    int tx = threadIdx.x & 31, ty = threadIdx.x >> 5;  // ty 0..7
    const float* ip = in + (size_t)d * Rr * Cc;
    float* op = out + (size_t)d * Rr * Cc;
#pragma unroll
    for (int i = 0; i < 32; i += 8)
        tile[ty + i][tx] = ip[(size_t)(tr * 32 + ty + i) * Cc + tc * 32 + tx];
    __syncthreads();
#pragma unroll
    for (int i = 0; i < 32; i += 8)
        op[(size_t)(tc * 32 + ty + i) * Rr + tr * 32 + tx] = tile[tx][ty + i];
}

extern "C" void kernel_launch(void* const* d_in, const int* in_sizes, int n_in,
                              void* d_out, int out_size, void* d_ws, size_t ws_size,
                              hipStream_t stream) {
    const float* x     = (const float*)d_in[0];
    const float* row_w = (const float*)d_in[1];
    const float* row_b = (const float*)d_in[2];
    const float* col_w = (const float*)d_in[3];
    const float* col_b = (const float*)d_in[4];
    const float* ln1_w = (const float*)d_in[5];
    const float* ln1_b = (const float*)d_in[6];
    const float* ln2_w = (const float*)d_in[7];
    const float* ln2_b = (const float*)d_in[8];
    float* out = (float*)d_out;

    char* ws = (char*)d_ws;
    const size_t ysz = (size_t)NH * NPOS * CH * 2;   // 25.2 MB (== DCH*NPOS*2)
    const size_t abytes = (size_t)DCH * NPOS * 4;    // 50.3 MB
    f16_t* Yq = (f16_t*)ws;
    f16_t* Yk = (f16_t*)(ws + ysz);
    f16_t* Yv = (f16_t*)(ws + 2 * ysz);
    float* A  = (float*)(ws + 3 * ysz);
    float* T  = (float*)(ws + 3 * ysz + abytes);
    f16_t* Xp = (f16_t*)(ws + 3 * ysz + 2 * abytes);
    f16_t* Wh = (f16_t*)(ws + 3 * ysz + 2 * abytes + ysz);

    dim3 ggrid(THREE_D / 128, NPOS / 128);   // x = o-tile (9), y = p-tile (256)
    const int wn4 = THREE_D * DCH / 4;
    dim3 cgrid(NPOS / 64, DCH / 64);

    // ---- stage 1: row attention (attend over L within each row s) ----
    conv_w<<<(wn4 + 255) / 256, 256, 0, stream>>>(row_w, Wh, wn4);
    conv_xT<<<cgrid, 256, 0, stream>>>(x, Xp);
    qkv_gemm_f16<<<ggrid, 256, 0, stream>>>(Wh, row_b, Xp, Yq, Yk, Yv);
    mfma_attn<LL><<<NH * SS, 256, 0, stream>>>(Yq, Yk, Yv, x, A);  // A = x + row_out
    chan_ln<<<NPOS / 256, 256, 0, stream>>>(A, ln1_w, ln1_b);      // A = out1
    transpose_dp<<<DCH * (SS / 32) * (LL / 32), 256, 0, stream>>>(A, T, SS, LL);

    // ---- stage 2: column attention (attend over S within each column l) ----
    conv_w<<<(wn4 + 255) / 256, 256, 0, stream>>>(col_w, Wh, wn4);
    conv_xT<<<cgrid, 256, 0, stream>>>(T, Xp);
    qkv_gemm_f16<<<ggrid, 256, 0, stream>>>(Wh, col_b, Xp, Yq, Yk, Yv);
    mfma_attn<SS><<<NH * LL, 256, 0, stream>>>(Yq, Yk, Yv, T, A);  // A = out1 + col_out (T-domain)
    chan_ln<<<NPOS / 256, 256, 0, stream>>>(A, ln2_w, ln2_b);      // A = out2 (T-domain)
    transpose_dp<<<DCH * (LL / 32) * (SS / 32), 256, 0, stream>>>(A, out, LL, SS);
}

// Round 5
// 407.940 us; speedup vs baseline: 4.0454x; 1.2979x over previous
//
#include <hip/hip_runtime.h>
#include <math.h>

#define DCH 384
#define NH 12
#define CH 32
#define SS 128
#define LL 256
#define NPOS 32768        // SS*LL
#define THREE_D 1152

typedef _Float16 f16_t;
typedef _Float16 f16x8 __attribute__((ext_vector_type(8)));
typedef float f32x4 __attribute__((ext_vector_type(4)));

// async global->LDS, 16B per lane; LDS dest = base + lane*16 (wave-uniform base)
#define GLD16(gptr, lptr) __builtin_amdgcn_global_load_lds( \
    (const __attribute__((address_space(1))) unsigned int*)(gptr), \
    (__attribute__((address_space(3))) unsigned int*)(lptr), 16, 0, 0)

// ---------------------------------------------------------------------------
// fp32 -> fp16 elementwise (weights, layout preserved). n4 = count/4.
// ---------------------------------------------------------------------------
__global__ __launch_bounds__(256) void conv_w(const float* __restrict__ in,
                                              f16_t* __restrict__ out, int n4) {
    int i = blockIdx.x * 256 + threadIdx.x;
    if (i < n4) {
        float4 v = ((const float4*)in)[i];
        unsigned short u0 = __builtin_bit_cast(unsigned short, (f16_t)v.x);
        unsigned short u1 = __builtin_bit_cast(unsigned short, (f16_t)v.y);
        unsigned short u2 = __builtin_bit_cast(unsigned short, (f16_t)v.z);
        unsigned short u3 = __builtin_bit_cast(unsigned short, (f16_t)v.w);
        uint2 r;
        r.x = (unsigned)u0 | ((unsigned)u1 << 16);
        r.y = (unsigned)u2 | ((unsigned)u3 << 16);
        ((uint2*)out)[i] = r;
    }
}

// ---------------------------------------------------------------------------
// fp32 [DCH][NPOS] -> fp16 [NPOS][DCH]  (transpose + convert, 64x64 tiles)
// ---------------------------------------------------------------------------
__global__ __launch_bounds__(256) void conv_xT(const float* __restrict__ in,
                                               f16_t* __restrict__ outp) {
    __shared__ float tile[64][65];
    const int p0 = blockIdx.x * 64;
    const int k0 = blockIdx.y * 64;
    const int tx = threadIdx.x & 63, ty = threadIdx.x >> 6;  // ty 0..3
#pragma unroll
    for (int i = 0; i < 16; ++i)
        tile[ty * 16 + i][tx] = in[(size_t)(k0 + ty * 16 + i) * NPOS + p0 + tx];
    __syncthreads();
    const int pr = threadIdx.x >> 2;   // 0..63 output row (p)
    const int cg = threadIdx.x & 3;    // 16-col group (k)
    union { uint4 v[2]; unsigned int u[8]; } res;
#pragma unroll
    for (int j = 0; j < 8; ++j) {
        unsigned short lo = __builtin_bit_cast(unsigned short, (f16_t)tile[cg * 16 + 2 * j][pr]);
        unsigned short hi = __builtin_bit_cast(unsigned short, (f16_t)tile[cg * 16 + 2 * j + 1][pr]);
        res.u[j] = (unsigned)lo | ((unsigned)hi << 16);
    }
    uint4* dst = (uint4*)&outp[(size_t)(p0 + pr) * DCH + k0 + cg * 16];
    dst[0] = res.v[0];
    dst[1] = res.v[1];
}

// ---------------------------------------------------------------------------
// fp16 MFMA GEMM producing attention-friendly fp16 outputs:
//   q,k -> Yq/Yk [NH][NPOS][CH]   (p-major rows of 32 ch: direct MFMA frags)
//   v   -> Yv [DCH][NPOS]         (c-major: V^T A-frag rows)
// ---------------------------------------------------------------------------
__global__ __launch_bounds__(256) void qkv_gemm_f16(
        const f16_t* __restrict__ Wh,    // [THREE_D][DCH]
        const float* __restrict__ bias,  // [THREE_D]
        const f16_t* __restrict__ Xp,    // [NPOS][DCH]
        f16_t* __restrict__ Yq, f16_t* __restrict__ Yk, f16_t* __restrict__ Yv)
{
    __shared__ f16_t sha[128 * 32];  // [o_local][k] row-major, 8 KB
    __shared__ f16_t shb[128 * 32];  // [p_local][k] row-major, 8 KB
    const int tid  = threadIdx.x;
    const int lane = tid & 63;
    const int wave = tid >> 6;
    const int ot   = blockIdx.x;       // 0..8
    const int o0 = ot * 128;
    const int p0 = blockIdx.y * 128;
    const int wr = wave >> 1, wc = wave & 1;   // 2x2 wave grid

    f32x4 acc[4][4] = {};

    const int c0 = wave * 128 + lane;
    const int c1 = c0 + 64;
    const f16_t* ga0 = Wh + (size_t)(o0 + (c0 >> 2)) * DCH + (c0 & 3) * 8;
    const f16_t* ga1 = Wh + (size_t)(o0 + (c1 >> 2)) * DCH + (c1 & 3) * 8;
    const f16_t* gb0 = Xp + (size_t)(p0 + (c0 >> 2)) * DCH + (c0 & 3) * 8;
    const f16_t* gb1 = Xp + (size_t)(p0 + (c1 >> 2)) * DCH + (c1 & 3) * 8;
    f16_t* la0 = sha + (wave * 128) * 8;
    f16_t* la1 = sha + (wave * 128 + 64) * 8;
    f16_t* lb0 = shb + (wave * 128) * 8;
    f16_t* lb1 = shb + (wave * 128 + 64) * 8;

    const int mrow = lane & 15;
    const int kg8  = (lane >> 4) * 8;

    for (int kk = 0; kk < DCH; kk += 32) {
        GLD16(ga0 + kk, la0);
        GLD16(ga1 + kk, la1);
        GLD16(gb0 + kk, lb0);
        GLD16(gb1 + kk, lb1);
        __syncthreads();
        f16x8 af[4], bfr[4];
#pragma unroll
        for (int mi = 0; mi < 4; ++mi)
            af[mi] = *(const f16x8*)(sha + (wr * 64 + mi * 16 + mrow) * 32 + kg8);
#pragma unroll
        for (int ni = 0; ni < 4; ++ni)
            bfr[ni] = *(const f16x8*)(shb + (wc * 64 + ni * 16 + mrow) * 32 + kg8);
#pragma unroll
        for (int mi = 0; mi < 4; ++mi)
#pragma unroll
            for (int ni = 0; ni < 4; ++ni)
                acc[mi][ni] = __builtin_amdgcn_mfma_f32_16x16x32_f16(
                    af[mi], bfr[ni], acc[mi][ni], 0, 0, 0);
        __syncthreads();
    }

    // C/D layout: col = lane&15 (p), row = (lane>>4)*4 + r (o)
    const int col = lane & 15;
    const int rq4 = (lane >> 4) * 4;
    const int qkv = ot / 3;     // 0=q 1=k 2=v
    const int grp = ot % 3;     // 128-block within the qkv group

    if (qkv < 2) {
        f16_t* Yt = (qkv == 0) ? Yq : Yk;
#pragma unroll
        for (int mi = 0; mi < 4; ++mi) {
            const int h  = grp * 4 + wr * 2 + (mi >> 1);
            const int cb = (mi & 1) * 16 + rq4;               // c base; +r consecutive
            const int ob = o0 + wr * 64 + mi * 16 + rq4;      // bias base
            const float b0 = bias[ob], b1 = bias[ob + 1];
            const float b2 = bias[ob + 2], b3 = bias[ob + 3];
#pragma unroll
            for (int ni = 0; ni < 4; ++ni) {
                const int p = p0 + wc * 64 + ni * 16 + col;
                union { uint2 u; f16_t h4[4]; } w;
                w.h4[0] = (f16_t)(acc[mi][ni][0] + b0);
                w.h4[1] = (f16_t)(acc[mi][ni][1] + b1);
                w.h4[2] = (f16_t)(acc[mi][ni][2] + b2);
                w.h4[3] = (f16_t)(acc[mi][ni][3] + b3);
                *(uint2*)(Yt + ((size_t)h * NPOS + p) * CH + cb) = w.u;
            }
        }
    } else {
#pragma unroll
        for (int mi = 0; mi < 4; ++mi) {
#pragma unroll
            for (int r = 0; r < 4; ++r) {
                const int cg = grp * 128 + wr * 64 + mi * 16 + rq4 + r;  // 0..383
                const float br = bias[768 + cg];
#pragma unroll
                for (int ni = 0; ni < 4; ++ni) {
                    const int p = p0 + wc * 64 + ni * 16 + col;
                    Yv[(size_t)cg * NPOS + p] = (f16_t)(acc[mi][ni][r] + br);
                }
            }
        }
    }
}

// ---------------------------------------------------------------------------
// MFMA axial attention (see round-4 comments). R = X + attn_out, [c][p].
// ---------------------------------------------------------------------------
template <int SEQ>
__global__ __launch_bounds__(256) void mfma_attn(
        const f16_t* __restrict__ Yq, const f16_t* __restrict__ Yk,
        const f16_t* __restrict__ Yv, const float* __restrict__ X,
        float* __restrict__ R)
{
    constexpr int JT  = SEQ / 16;    // j-tiles
    constexpr int NIT = SEQ / 64;    // i-tiles per wave
    constexpr int PST = SEQ + 8;     // padded P row stride (fp16 units)
    __shared__ f16_t pb[4][16 * PST];
    const int lane = threadIdx.x & 63;
    const int wave = threadIdx.x >> 6;
    const int col = lane & 15, quad = lane >> 4;
    const int h = blockIdx.x % NH;
    const size_t pbase = (size_t)(blockIdx.x / NH) * SEQ;

    const f16_t* qg = Yq + ((size_t)h * NPOS + pbase) * CH;
    const f16_t* kg = Yk + ((size_t)h * NPOS + pbase) * CH;
    const f16_t* vg = Yv + (size_t)h * CH * NPOS + pbase;
    f16_t* mypb = pb[wave];

    for (int it = 0; it < NIT; ++it) {
        const int i0 = (wave * NIT + it) * 16;
        const f16x8 qf = *(const f16x8*)(qg + (size_t)(i0 + col) * CH + quad * 8);
        f32x4 st[JT];
#pragma unroll
        for (int mt = 0; mt < JT; ++mt) {
            f16x8 kf = *(const f16x8*)(kg + (size_t)(mt * 16 + col) * CH + quad * 8);
            st[mt] = __builtin_amdgcn_mfma_f32_16x16x32_f16(kf, qf, (f32x4){0.f, 0.f, 0.f, 0.f}, 0, 0, 0);
        }
        float sum = 0.f;
#pragma unroll
        for (int mt = 0; mt < JT; ++mt)
#pragma unroll
            for (int r = 0; r < 4; ++r) {
                st[mt][r] = __expf(st[mt][r]);
                sum += st[mt][r];
            }
        sum += __shfl_xor(sum, 16, 64);
        sum += __shfl_xor(sum, 32, 64);
        const float inv = 1.f / sum;
#pragma unroll
        for (int mt = 0; mt < JT; ++mt) {
            union { uint2 u; f16_t h4[4]; } w;
            w.h4[0] = (f16_t)(st[mt][0] * inv);
            w.h4[1] = (f16_t)(st[mt][1] * inv);
            w.h4[2] = (f16_t)(st[mt][2] * inv);
            w.h4[3] = (f16_t)(st[mt][3] * inv);
            *(uint2*)(mypb + col * PST + mt * 16 + quad * 4) = w.u;
        }
        __syncthreads();   // drain LDS writes (cross-lane read next)

        f32x4 ot0 = {0.f, 0.f, 0.f, 0.f}, ot1 = {0.f, 0.f, 0.f, 0.f};
#pragma unroll
        for (int ks = 0; ks < SEQ / 32; ++ks) {
            f16x8 pf = *(const f16x8*)(mypb + col * PST + ks * 32 + quad * 8);
            f16x8 v0 = *(const f16x8*)(vg + (size_t)col * NPOS + ks * 32 + quad * 8);
            f16x8 v1 = *(const f16x8*)(vg + (size_t)(16 + col) * NPOS + ks * 32 + quad * 8);
            ot0 = __builtin_amdgcn_mfma_f32_16x16x32_f16(v0, pf, ot0, 0, 0, 0);
            ot1 = __builtin_amdgcn_mfma_f32_16x16x32_f16(v1, pf, ot1, 0, 0, 0);
        }
        const size_t pos = pbase + i0 + col;
#pragma unroll
        for (int r = 0; r < 4; ++r) {
            const size_t c0r = (size_t)(h * CH + quad * 4 + r) * NPOS + pos;
            const size_t c1r = (size_t)(h * CH + 16 + quad * 4 + r) * NPOS + pos;
            R[c0r] = X[c0r] + ot0[r];
            R[c1r] = X[c1r] + ot1[r];
        }
        __syncthreads();   // keep waves in step before pb reuse
    }
}

// ---------------------------------------------------------------------------
// LN stats: mu[p], rs[p] over the 384 channels of A[d][p].
// 512 blocks x 256 threads: 4 waves each sum a 96-channel group for 64
// positions (coalesced 256B per instruction), LDS combine.
// ---------------------------------------------------------------------------
__global__ __launch_bounds__(256) void ln_stats(const float* __restrict__ A,
                                                float* __restrict__ mu,
                                                float* __restrict__ rs) {
    __shared__ float ssum[4][64], ssq[4][64];
    const int i = threadIdx.x & 63;
    const int g = threadIdx.x >> 6;
    const int p = blockIdx.x * 64 + i;
    float sum = 0.f, sq = 0.f;
    const float* ap = A + (size_t)(g * 96) * NPOS + p;
#pragma unroll 4
    for (int d = 0; d < 96; ++d) {
        float v = ap[(size_t)d * NPOS];
        sum += v;
        sq += v * v;
    }
    ssum[g][i] = sum;
    ssq[g][i] = sq;
    __syncthreads();
    if (g == 0) {
        float s = ssum[0][i] + ssum[1][i] + ssum[2][i] + ssum[3][i];
        float q = ssq[0][i] + ssq[1][i] + ssq[2][i] + ssq[3][i];
        float m = s * (1.f / DCH);
        float var = q * (1.f / DCH) - m * m;
        mu[p] = m;
        rs[p] = rsqrtf(var + 1e-5f);
    }
}

// ---------------------------------------------------------------------------
// Fused normalize + per-channel transpose:
//   out[d][c][r] = (in[d][r][c] - mu[r*Cc+c]) * rs[r*Cc+c] * w[d] + b[d]
// Normalization applied at load time (consecutive lanes = consecutive pos ->
// coalesced mu/rs reads).
// ---------------------------------------------------------------------------
__global__ __launch_bounds__(256) void norm_transpose(
        const float* __restrict__ in, const float* __restrict__ mu,
        const float* __restrict__ rs, const float* __restrict__ w,
        const float* __restrict__ b, float* __restrict__ out, int Rr, int Cc) {
    __shared__ float tile[32][33];
    const int ntc = Cc >> 5, ntr = Rr >> 5;
    int tc = blockIdx.x % ntc;
    int tr = (blockIdx.x / ntc) % ntr;
    int d = blockIdx.x / (ntc * ntr);
    int tx = threadIdx.x & 31, ty = threadIdx.x >> 5;  // ty 0..7
    const float* ip = in + (size_t)d * Rr * Cc;
    float* op = out + (size_t)d * Rr * Cc;
    const float wd = w[d], bd = b[d];
#pragma unroll
    for (int i = 0; i < 32; i += 8) {
        const int r = tr * 32 + ty + i;
        const int c = tc * 32 + tx;
        const int pos = r * Cc + c;
        float v = ip[(size_t)r * Cc + c];
        tile[ty + i][tx] = (v - mu[pos]) * rs[pos] * wd + bd;
    }
    __syncthreads();
#pragma unroll
    for (int i = 0; i < 32; i += 8)
        op[(size_t)(tc * 32 + ty + i) * Rr + tr * 32 + tx] = tile[tx][ty + i];
}

extern "C" void kernel_launch(void* const* d_in, const int* in_sizes, int n_in,
                              void* d_out, int out_size, void* d_ws, size_t ws_size,
                              hipStream_t stream) {
    const float* x     = (const float*)d_in[0];
    const float* row_w = (const float*)d_in[1];
    const float* row_b = (const float*)d_in[2];
    const float* col_w = (const float*)d_in[3];
    const float* col_b = (const float*)d_in[4];
    const float* ln1_w = (const float*)d_in[5];
    const float* ln1_b = (const float*)d_in[6];
    const float* ln2_w = (const float*)d_in[7];
    const float* ln2_b = (const float*)d_in[8];
    float* out = (float*)d_out;

    char* ws = (char*)d_ws;
    const size_t ysz = (size_t)NH * NPOS * CH * 2;   // 25.2 MB (== DCH*NPOS*2)
    const size_t abytes = (size_t)DCH * NPOS * 4;    // 50.3 MB
    f16_t* Yq = (f16_t*)ws;
    f16_t* Yk = (f16_t*)(ws + ysz);
    f16_t* Yv = (f16_t*)(ws + 2 * ysz);
    float* A  = (float*)(ws + 3 * ysz);
    float* T  = (float*)(ws + 3 * ysz + abytes);
    f16_t* Xp = (f16_t*)(ws + 3 * ysz + 2 * abytes);
    f16_t* Wh = (f16_t*)(ws + 3 * ysz + 2 * abytes + ysz);
    float* MU = (float*)(ws + 3 * ysz + 2 * abytes + ysz + (1 << 21));
    float* RS = MU + NPOS;

    dim3 ggrid(THREE_D / 128, NPOS / 128);   // x = o-tile (9), y = p-tile (256)
    const int wn4 = THREE_D * DCH / 4;
    dim3 cgrid(NPOS / 64, DCH / 64);

    // ---- stage 1: row attention (attend over L within each row s) ----
    conv_w<<<(wn4 + 255) / 256, 256, 0, stream>>>(row_w, Wh, wn4);
    conv_xT<<<cgrid, 256, 0, stream>>>(x, Xp);
    qkv_gemm_f16<<<ggrid, 256, 0, stream>>>(Wh, row_b, Xp, Yq, Yk, Yv);
    mfma_attn<LL><<<NH * SS, 256, 0, stream>>>(Yq, Yk, Yv, x, A);  // A = x + row_out
    ln_stats<<<NPOS / 64, 256, 0, stream>>>(A, MU, RS);
    norm_transpose<<<DCH * (SS / 32) * (LL / 32), 256, 0, stream>>>(
        A, MU, RS, ln1_w, ln1_b, T, SS, LL);                       // T = out1^T

    // ---- stage 2: column attention (attend over S within each column l) ----
    conv_w<<<(wn4 + 255) / 256, 256, 0, stream>>>(col_w, Wh, wn4);
    conv_xT<<<cgrid, 256, 0, stream>>>(T, Xp);
    qkv_gemm_f16<<<ggrid, 256, 0, stream>>>(Wh, col_b, Xp, Yq, Yk, Yv);
    mfma_attn<SS><<<NH * LL, 256, 0, stream>>>(Yq, Yk, Yv, T, A);  // A = out1 + col_out (T-domain)
    ln_stats<<<NPOS / 64, 256, 0, stream>>>(A, MU, RS);
    norm_transpose<<<DCH * (LL / 32) * (SS / 32), 256, 0, stream>>>(
        A, MU, RS, ln2_w, ln2_b, out, LL, SS);                     // out = out2^T
}

// Round 6
// 394.392 us; speedup vs baseline: 4.1844x; 1.0344x over previous
//
#include <hip/hip_runtime.h>
#include <math.h>

#define DCH 384
#define NH 12
#define CH 32
#define SS 128
#define LL 256
#define NPOS 32768        // SS*LL
#define THREE_D 1152

typedef _Float16 f16_t;
typedef _Float16 f16x4 __attribute__((ext_vector_type(4)));
typedef _Float16 f16x8 __attribute__((ext_vector_type(8)));
typedef float f32x4 __attribute__((ext_vector_type(4)));

// async global->LDS, 16B per lane; LDS dest = base + lane*16 (wave-uniform base)
#define GLD16(gptr, lptr) __builtin_amdgcn_global_load_lds( \
    (const __attribute__((address_space(1))) unsigned int*)(gptr), \
    (__attribute__((address_space(3))) unsigned int*)(lptr), 16, 0, 0)

// wave-local LDS drain: same-wave cross-lane ds_write -> ds_read ordering.
// (pb regions are per-wave; no cross-wave hazard, so no s_barrier needed.)
#define WAVE_LDS_FENCE() __asm__ volatile("s_waitcnt lgkmcnt(0)" ::: "memory")

// ---------------------------------------------------------------------------
// fp32 -> fp16 elementwise (weights, layout preserved). n4 = count/4.
// ---------------------------------------------------------------------------
__global__ __launch_bounds__(256) void conv_w(const float* __restrict__ in,
                                              f16_t* __restrict__ out, int n4) {
    int i = blockIdx.x * 256 + threadIdx.x;
    if (i < n4) {
        float4 v = ((const float4*)in)[i];
        unsigned short u0 = __builtin_bit_cast(unsigned short, (f16_t)v.x);
        unsigned short u1 = __builtin_bit_cast(unsigned short, (f16_t)v.y);
        unsigned short u2 = __builtin_bit_cast(unsigned short, (f16_t)v.z);
        unsigned short u3 = __builtin_bit_cast(unsigned short, (f16_t)v.w);
        uint2 r;
        r.x = (unsigned)u0 | ((unsigned)u1 << 16);
        r.y = (unsigned)u2 | ((unsigned)u3 << 16);
        ((uint2*)out)[i] = r;
    }
}

// ---------------------------------------------------------------------------
// fp32 [DCH][NPOS] -> fp16 [NPOS][DCH]  (transpose + convert, 64x64 tiles)
// ---------------------------------------------------------------------------
__global__ __launch_bounds__(256) void conv_xT(const float* __restrict__ in,
                                               f16_t* __restrict__ outp) {
    __shared__ float tile[64][65];
    const int p0 = blockIdx.x * 64;
    const int k0 = blockIdx.y * 64;
    const int tx = threadIdx.x & 63, ty = threadIdx.x >> 6;  // ty 0..3
#pragma unroll
    for (int i = 0; i < 16; ++i)
        tile[ty * 16 + i][tx] = in[(size_t)(k0 + ty * 16 + i) * NPOS + p0 + tx];
    __syncthreads();
    const int pr = threadIdx.x >> 2;   // 0..63 output row (p)
    const int cg = threadIdx.x & 3;    // 16-col group (k)
    union { uint4 v[2]; unsigned int u[8]; } res;
#pragma unroll
    for (int j = 0; j < 8; ++j) {
        unsigned short lo = __builtin_bit_cast(unsigned short, (f16_t)tile[cg * 16 + 2 * j][pr]);
        unsigned short hi = __builtin_bit_cast(unsigned short, (f16_t)tile[cg * 16 + 2 * j + 1][pr]);
        res.u[j] = (unsigned)lo | ((unsigned)hi << 16);
    }
    uint4* dst = (uint4*)&outp[(size_t)(p0 + pr) * DCH + k0 + cg * 16];
    dst[0] = res.v[0];
    dst[1] = res.v[1];
}

// ---------------------------------------------------------------------------
// fp16 MFMA GEMM producing attention-friendly fp16 outputs:
//   q,k -> Yq/Yk [NH][NPOS][CH]   (p-major rows of 32 ch: direct MFMA frags)
//   v   -> Yv [DCH][NPOS]         (c-major: V^T A-frag rows)
// ---------------------------------------------------------------------------
__global__ __launch_bounds__(256) void qkv_gemm_f16(
        const f16_t* __restrict__ Wh,    // [THREE_D][DCH]
        const float* __restrict__ bias,  // [THREE_D]
        const f16_t* __restrict__ Xp,    // [NPOS][DCH]
        f16_t* __restrict__ Yq, f16_t* __restrict__ Yk, f16_t* __restrict__ Yv)
{
    __shared__ f16_t sha[128 * 32];  // [o_local][k] row-major, 8 KB
    __shared__ f16_t shb[128 * 32];  // [p_local][k] row-major, 8 KB
    const int tid  = threadIdx.x;
    const int lane = tid & 63;
    const int wave = tid >> 6;
    const int ot   = blockIdx.x;       // 0..8
    const int o0 = ot * 128;
    const int p0 = blockIdx.y * 128;
    const int wr = wave >> 1, wc = wave & 1;   // 2x2 wave grid

    f32x4 acc[4][4] = {};

    const int c0 = wave * 128 + lane;
    const int c1 = c0 + 64;
    const f16_t* ga0 = Wh + (size_t)(o0 + (c0 >> 2)) * DCH + (c0 & 3) * 8;
    const f16_t* ga1 = Wh + (size_t)(o0 + (c1 >> 2)) * DCH + (c1 & 3) * 8;
    const f16_t* gb0 = Xp + (size_t)(p0 + (c0 >> 2)) * DCH + (c0 & 3) * 8;
    const f16_t* gb1 = Xp + (size_t)(p0 + (c1 >> 2)) * DCH + (c1 & 3) * 8;
    f16_t* la0 = sha + (wave * 128) * 8;
    f16_t* la1 = sha + (wave * 128 + 64) * 8;
    f16_t* lb0 = shb + (wave * 128) * 8;
    f16_t* lb1 = shb + (wave * 128 + 64) * 8;

    const int mrow = lane & 15;
    const int kg8  = (lane >> 4) * 8;

    for (int kk = 0; kk < DCH; kk += 32) {
        GLD16(ga0 + kk, la0);
        GLD16(ga1 + kk, la1);
        GLD16(gb0 + kk, lb0);
        GLD16(gb1 + kk, lb1);
        __syncthreads();
        f16x8 af[4], bfr[4];
#pragma unroll
        for (int mi = 0; mi < 4; ++mi)
            af[mi] = *(const f16x8*)(sha + (wr * 64 + mi * 16 + mrow) * 32 + kg8);
#pragma unroll
        for (int ni = 0; ni < 4; ++ni)
            bfr[ni] = *(const f16x8*)(shb + (wc * 64 + ni * 16 + mrow) * 32 + kg8);
#pragma unroll
        for (int mi = 0; mi < 4; ++mi)
#pragma unroll
            for (int ni = 0; ni < 4; ++ni)
                acc[mi][ni] = __builtin_amdgcn_mfma_f32_16x16x32_f16(
                    af[mi], bfr[ni], acc[mi][ni], 0, 0, 0);
        __syncthreads();
    }

    // C/D layout: col = lane&15 (p), row = (lane>>4)*4 + r (o)
    const int col = lane & 15;
    const int rq4 = (lane >> 4) * 4;
    const int qkv = ot / 3;     // 0=q 1=k 2=v
    const int grp = ot % 3;     // 128-block within the qkv group

    if (qkv < 2) {
        f16_t* Yt = (qkv == 0) ? Yq : Yk;
#pragma unroll
        for (int mi = 0; mi < 4; ++mi) {
            const int h  = grp * 4 + wr * 2 + (mi >> 1);
            const int cb = (mi & 1) * 16 + rq4;               // c base; +r consecutive
            const int ob = o0 + wr * 64 + mi * 16 + rq4;      // bias base
            const float b0 = bias[ob], b1 = bias[ob + 1];
            const float b2 = bias[ob + 2], b3 = bias[ob + 3];
#pragma unroll
            for (int ni = 0; ni < 4; ++ni) {
                const int p = p0 + wc * 64 + ni * 16 + col;
                union { uint2 u; f16_t h4[4]; } w;
                w.h4[0] = (f16_t)(acc[mi][ni][0] + b0);
                w.h4[1] = (f16_t)(acc[mi][ni][1] + b1);
                w.h4[2] = (f16_t)(acc[mi][ni][2] + b2);
                w.h4[3] = (f16_t)(acc[mi][ni][3] + b3);
                *(uint2*)(Yt + ((size_t)h * NPOS + p) * CH + cb) = w.u;
            }
        }
    } else {
#pragma unroll
        for (int mi = 0; mi < 4; ++mi) {
#pragma unroll
            for (int r = 0; r < 4; ++r) {
                const int cg = grp * 128 + wr * 64 + mi * 16 + rq4 + r;  // 0..383
                const float br = bias[768 + cg];
#pragma unroll
                for (int ni = 0; ni < 4; ++ni) {
                    const int p = p0 + wc * 64 + ni * 16 + col;
                    Yv[(size_t)cg * NPOS + p] = (f16_t)(acc[mi][ni][r] + br);
                }
            }
        }
    }
}

// ---------------------------------------------------------------------------
// MFMA axial attention, BARRIER-FREE (pb is per-wave; wave-local lgkmcnt
// drain replaces __syncthreads so the 4 waves free-run).
// XT16=false: residual X is fp32 [c][p] (stage 1, X = x).
// XT16=true : residual X is fp16 [p][DCH] (stage 2, X = Xp = normalized out1).
// R = X + attn_out, fp32 [c][p].
// ---------------------------------------------------------------------------
template <int SEQ, bool XT16>
__global__ __launch_bounds__(256) void mfma_attn(
        const f16_t* __restrict__ Yq, const f16_t* __restrict__ Yk,
        const f16_t* __restrict__ Yv, const void* __restrict__ Xv_,
        float* __restrict__ R)
{
    constexpr int JT  = SEQ / 16;    // j-tiles
    constexpr int NIT = SEQ / 64;    // i-tiles per wave
    constexpr int PST = SEQ + 8;     // padded P row stride (fp16 units)
    __shared__ f16_t pb[4][16 * PST];
    const int lane = threadIdx.x & 63;
    const int wave = threadIdx.x >> 6;
    const int col = lane & 15, quad = lane >> 4;
    const int h = blockIdx.x % NH;
    const size_t pbase = (size_t)(blockIdx.x / NH) * SEQ;

    const f16_t* qg = Yq + ((size_t)h * NPOS + pbase) * CH;
    const f16_t* kg = Yk + ((size_t)h * NPOS + pbase) * CH;
    const f16_t* vg = Yv + (size_t)h * CH * NPOS + pbase;
    f16_t* mypb = pb[wave];

    for (int it = 0; it < NIT; ++it) {
        const int i0 = (wave * NIT + it) * 16;
        const f16x8 qf = *(const f16x8*)(qg + (size_t)(i0 + col) * CH + quad * 8);
        f32x4 st[JT];
#pragma unroll
        for (int mt = 0; mt < JT; ++mt) {
            f16x8 kf = *(const f16x8*)(kg + (size_t)(mt * 16 + col) * CH + quad * 8);
            st[mt] = __builtin_amdgcn_mfma_f32_16x16x32_f16(kf, qf, (f32x4){0.f, 0.f, 0.f, 0.f}, 0, 0, 0);
        }
        float sum = 0.f;
#pragma unroll
        for (int mt = 0; mt < JT; ++mt)
#pragma unroll
            for (int r = 0; r < 4; ++r) {
                st[mt][r] = __expf(st[mt][r]);
                sum += st[mt][r];
            }
        sum += __shfl_xor(sum, 16, 64);
        sum += __shfl_xor(sum, 32, 64);
        const float inv = 1.f / sum;
#pragma unroll
        for (int mt = 0; mt < JT; ++mt) {
            union { uint2 u; f16_t h4[4]; } w;
            w.h4[0] = (f16_t)(st[mt][0] * inv);
            w.h4[1] = (f16_t)(st[mt][1] * inv);
            w.h4[2] = (f16_t)(st[mt][2] * inv);
            w.h4[3] = (f16_t)(st[mt][3] * inv);
            *(uint2*)(mypb + col * PST + mt * 16 + quad * 4) = w.u;
        }
        WAVE_LDS_FENCE();   // drain same-wave ds_writes before cross-lane reads

        f32x4 ot0 = {0.f, 0.f, 0.f, 0.f}, ot1 = {0.f, 0.f, 0.f, 0.f};
#pragma unroll
        for (int ks = 0; ks < SEQ / 32; ++ks) {
            f16x8 pf = *(const f16x8*)(mypb + col * PST + ks * 32 + quad * 8);
            f16x8 v0 = *(const f16x8*)(vg + (size_t)col * NPOS + ks * 32 + quad * 8);
            f16x8 v1 = *(const f16x8*)(vg + (size_t)(16 + col) * NPOS + ks * 32 + quad * 8);
            ot0 = __builtin_amdgcn_mfma_f32_16x16x32_f16(v0, pf, ot0, 0, 0, 0);
            ot1 = __builtin_amdgcn_mfma_f32_16x16x32_f16(v1, pf, ot1, 0, 0, 0);
        }
        const size_t pos = pbase + i0 + col;
        if constexpr (XT16) {
            const f16_t* Xh = (const f16_t*)Xv_;
            const f16x4 xa = *(const f16x4*)(Xh + pos * DCH + h * CH + quad * 4);
            const f16x4 xb = *(const f16x4*)(Xh + pos * DCH + h * CH + 16 + quad * 4);
#pragma unroll
            for (int r = 0; r < 4; ++r) {
                R[(size_t)(h * CH + quad * 4 + r) * NPOS + pos]      = (float)xa[r] + ot0[r];
                R[(size_t)(h * CH + 16 + quad * 4 + r) * NPOS + pos] = (float)xb[r] + ot1[r];
            }
        } else {
            const float* Xf = (const float*)Xv_;
#pragma unroll
            for (int r = 0; r < 4; ++r) {
                const size_t c0r = (size_t)(h * CH + quad * 4 + r) * NPOS + pos;
                const size_t c1r = (size_t)(h * CH + 16 + quad * 4 + r) * NPOS + pos;
                R[c0r] = Xf[c0r] + ot0[r];
                R[c1r] = Xf[c1r] + ot1[r];
            }
        }
    }
}

// ---------------------------------------------------------------------------
// LN stats: mu[p], rs[p] over the 384 channels of A[d][p].
// ---------------------------------------------------------------------------
__global__ __launch_bounds__(256) void ln_stats(const float* __restrict__ A,
                                                float* __restrict__ mu,
                                                float* __restrict__ rs) {
    __shared__ float ssum[4][64], ssq[4][64];
    const int i = threadIdx.x & 63;
    const int g = threadIdx.x >> 6;
    const int p = blockIdx.x * 64 + i;
    float sum = 0.f, sq = 0.f;
    const float* ap = A + (size_t)(g * 96) * NPOS + p;
#pragma unroll 4
    for (int d = 0; d < 96; ++d) {
        float v = ap[(size_t)d * NPOS];
        sum += v;
        sq += v * v;
    }
    ssum[g][i] = sum;
    ssq[g][i] = sq;
    __syncthreads();
    if (g == 0) {
        float s = ssum[0][i] + ssum[1][i] + ssum[2][i] + ssum[3][i];
        float q = ssq[0][i] + ssq[1][i] + ssq[2][i] + ssq[3][i];
        float m = s * (1.f / DCH);
        float var = q * (1.f / DCH) - m * m;
        mu[p] = m;
        rs[p] = rsqrtf(var + 1e-5f);
    }
}

// ---------------------------------------------------------------------------
// Fused LN-apply + transpose + fp16: A fp32 [d][s*LL+l] -> Xp fp16
// [(l*SS+s)][d].  Block: 64 d x 64 l at fixed s.  mu/rs per position
// (coalesced over l), w/b per d (row-uniform).
// ---------------------------------------------------------------------------
__global__ __launch_bounds__(256) void norm_xT(
        const float* __restrict__ A, const float* __restrict__ mu,
        const float* __restrict__ rs, const float* __restrict__ w,
        const float* __restrict__ b, f16_t* __restrict__ Xp) {
    __shared__ float tile[64][65];
    const int l0 = (blockIdx.x & 3) * 64;          // LL/64 = 4
    const int s  = (blockIdx.x >> 2) & (SS - 1);   // 128
    const int k0 = (blockIdx.x >> 9) * 64;         // DCH/64 = 6
    const int tx = threadIdx.x & 63, ty = threadIdx.x >> 6;  // ty 0..3
    const int pos0 = s * LL + l0;
#pragma unroll
    for (int i = 0; i < 16; ++i) {
        const int d = k0 + ty * 16 + i;
        float v = A[(size_t)d * NPOS + pos0 + tx];
        tile[ty * 16 + i][tx] = (v - mu[pos0 + tx]) * rs[pos0 + tx] * w[d] + b[d];
    }
    __syncthreads();
    const int pr = threadIdx.x >> 2;   // l-offset 0..63
    const int cg = threadIdx.x & 3;    // 16-d group
    union { uint4 v[2]; unsigned int u[8]; } res;
#pragma unroll
    for (int j = 0; j < 8; ++j) {
        unsigned short lo = __builtin_bit_cast(unsigned short, (f16_t)tile[cg * 16 + 2 * j][pr]);
        unsigned short hi = __builtin_bit_cast(unsigned short, (f16_t)tile[cg * 16 + 2 * j + 1][pr]);
        res.u[j] = (unsigned)lo | ((unsigned)hi << 16);
    }
    uint4* dst = (uint4*)&Xp[(size_t)((l0 + pr) * SS + s) * DCH + k0 + cg * 16];
    dst[0] = res.v[0];
    dst[1] = res.v[1];
}

// ---------------------------------------------------------------------------
// Final: normalize + per-channel transpose back to original domain:
// A fp32 [d][l*SS+s] -> out fp32 [d][s*LL+l].
// ---------------------------------------------------------------------------
__global__ __launch_bounds__(256) void norm_transpose(
        const float* __restrict__ in, const float* __restrict__ mu,
        const float* __restrict__ rs, const float* __restrict__ w,
        const float* __restrict__ b, float* __restrict__ out, int Rr, int Cc) {
    __shared__ float tile[32][33];
    const int ntc = Cc >> 5, ntr = Rr >> 5;
    int tc = blockIdx.x % ntc;
    int tr = (blockIdx.x / ntc) % ntr;
    int d = blockIdx.x / (ntc * ntr);
    int tx = threadIdx.x & 31, ty = threadIdx.x >> 5;  // ty 0..7
    const float* ip = in + (size_t)d * Rr * Cc;
    float* op = out + (size_t)d * Rr * Cc;
    const float wd = w[d], bd = b[d];
#pragma unroll
    for (int i = 0; i < 32; i += 8) {
        const int r = tr * 32 + ty + i;
        const int c = tc * 32 + tx;
        const int pos = r * Cc + c;
        float v = ip[(size_t)r * Cc + c];
        tile[ty + i][tx] = (v - mu[pos]) * rs[pos] * wd + bd;
    }
    __syncthreads();
#pragma unroll
    for (int i = 0; i < 32; i += 8)
        op[(size_t)(tc * 32 + ty + i) * Rr + tr * 32 + tx] = tile[tx][ty + i];
}

extern "C" void kernel_launch(void* const* d_in, const int* in_sizes, int n_in,
                              void* d_out, int out_size, void* d_ws, size_t ws_size,
                              hipStream_t stream) {
    const float* x     = (const float*)d_in[0];
    const float* row_w = (const float*)d_in[1];
    const float* row_b = (const float*)d_in[2];
    const float* col_w = (const float*)d_in[3];
    const float* col_b = (const float*)d_in[4];
    const float* ln1_w = (const float*)d_in[5];
    const float* ln1_b = (const float*)d_in[6];
    const float* ln2_w = (const float*)d_in[7];
    const float* ln2_b = (const float*)d_in[8];
    float* out = (float*)d_out;

    char* ws = (char*)d_ws;
    const size_t ysz = (size_t)NH * NPOS * CH * 2;   // 25.2 MB (== DCH*NPOS*2)
    const size_t abytes = (size_t)DCH * NPOS * 4;    // 50.3 MB
    f16_t* Yq = (f16_t*)ws;
    f16_t* Yk = (f16_t*)(ws + ysz);
    f16_t* Yv = (f16_t*)(ws + 2 * ysz);
    float* A  = (float*)(ws + 3 * ysz);
    f16_t* Xp = (f16_t*)(ws + 3 * ysz + abytes);
    f16_t* Wh = (f16_t*)(ws + 3 * ysz + abytes + ysz);
    float* MU = (float*)(ws + 3 * ysz + abytes + ysz + (1 << 21));
    float* RS = MU + NPOS;

    dim3 ggrid(THREE_D / 128, NPOS / 128);   // x = o-tile (9), y = p-tile (256)
    const int wn4 = THREE_D * DCH / 4;
    dim3 cgrid(NPOS / 64, DCH / 64);

    // ---- stage 1: row attention (attend over L within each row s) ----
    conv_w<<<(wn4 + 255) / 256, 256, 0, stream>>>(row_w, Wh, wn4);
    conv_xT<<<cgrid, 256, 0, stream>>>(x, Xp);
    qkv_gemm_f16<<<ggrid, 256, 0, stream>>>(Wh, row_b, Xp, Yq, Yk, Yv);
    mfma_attn<LL, false><<<NH * SS, 256, 0, stream>>>(Yq, Yk, Yv, x, A);  // A = x + row_out
    ln_stats<<<NPOS / 64, 256, 0, stream>>>(A, MU, RS);
    // Xp = LN1(A) transposed to T-domain [p'][d], fp16 (feeds GEMM + residual)
    norm_xT<<<(DCH / 64) * SS * (LL / 64), 256, 0, stream>>>(A, MU, RS, ln1_w, ln1_b, Xp);

    // ---- stage 2: column attention (attend over S within each column l) ----
    conv_w<<<(wn4 + 255) / 256, 256, 0, stream>>>(col_w, Wh, wn4);
    qkv_gemm_f16<<<ggrid, 256, 0, stream>>>(Wh, col_b, Xp, Yq, Yk, Yv);
    mfma_attn<SS, true><<<NH * LL, 256, 0, stream>>>(Yq, Yk, Yv, Xp, A);  // A = out1 + col_out (T-domain)
    ln_stats<<<NPOS / 64, 256, 0, stream>>>(A, MU, RS);
    norm_transpose<<<DCH * (LL / 32) * (SS / 32), 256, 0, stream>>>(
        A, MU, RS, ln2_w, ln2_b, out, LL, SS);                     // out = out2 re-transposed
}

// Round 8
// 366.550 us; speedup vs baseline: 4.5022x; 1.0760x over previous
//
#include <hip/hip_runtime.h>
#include <math.h>

#define DCH 384
#define NH 12
#define CH 32
#define SS 128
#define LL 256
#define NPOS 32768        // SS*LL
#define THREE_D 1152

typedef _Float16 f16_t;
typedef _Float16 f16x4 __attribute__((ext_vector_type(4)));
typedef _Float16 f16x8 __attribute__((ext_vector_type(8)));
typedef float f32x4 __attribute__((ext_vector_type(4)));

// async global->LDS, 16B per lane.
// SOURCE: per-lane global address (must include lane term yourself!)
// DEST:   wave-uniform LDS base; HW adds lane*16.
#define GLD16(gptr, lptr) __builtin_amdgcn_global_load_lds( \
    (const __attribute__((address_space(1))) unsigned int*)(gptr), \
    (__attribute__((address_space(3))) unsigned int*)(lptr), 16, 0, 0)

// wave-local LDS drain: same-wave cross-lane ds_write -> ds_read ordering.
#define WAVE_LDS_FENCE() __asm__ volatile("s_waitcnt lgkmcnt(0)" ::: "memory")

// ---------------------------------------------------------------------------
// fp32 -> fp16 elementwise (weights, layout preserved). n4 = count/4.
// ---------------------------------------------------------------------------
__global__ __launch_bounds__(256) void conv_w(const float* __restrict__ in,
                                              f16_t* __restrict__ out, int n4) {
    int i = blockIdx.x * 256 + threadIdx.x;
    if (i < n4) {
        float4 v = ((const float4*)in)[i];
        unsigned short u0 = __builtin_bit_cast(unsigned short, (f16_t)v.x);
        unsigned short u1 = __builtin_bit_cast(unsigned short, (f16_t)v.y);
        unsigned short u2 = __builtin_bit_cast(unsigned short, (f16_t)v.z);
        unsigned short u3 = __builtin_bit_cast(unsigned short, (f16_t)v.w);
        uint2 r;
        r.x = (unsigned)u0 | ((unsigned)u1 << 16);
        r.y = (unsigned)u2 | ((unsigned)u3 << 16);
        ((uint2*)out)[i] = r;
    }
}

// ---------------------------------------------------------------------------
// fp32 [DCH][NPOS] -> fp16 [NPOS][DCH]  (transpose + convert, 64x64 tiles)
// ---------------------------------------------------------------------------
__global__ __launch_bounds__(256) void conv_xT(const float* __restrict__ in,
                                               f16_t* __restrict__ outp) {
    __shared__ float tile[64][65];
    const int p0 = blockIdx.x * 64;
    const int k0 = blockIdx.y * 64;
    const int tx = threadIdx.x & 63, ty = threadIdx.x >> 6;  // ty 0..3
#pragma unroll
    for (int i = 0; i < 16; ++i)
        tile[ty * 16 + i][tx] = in[(size_t)(k0 + ty * 16 + i) * NPOS + p0 + tx];
    __syncthreads();
    const int pr = threadIdx.x >> 2;   // 0..63 output row (p)
    const int cg = threadIdx.x & 3;    // 16-col group (k)
    union { uint4 v[2]; unsigned int u[8]; } res;
#pragma unroll
    for (int j = 0; j < 8; ++j) {
        unsigned short lo = __builtin_bit_cast(unsigned short, (f16_t)tile[cg * 16 + 2 * j][pr]);
        unsigned short hi = __builtin_bit_cast(unsigned short, (f16_t)tile[cg * 16 + 2 * j + 1][pr]);
        res.u[j] = (unsigned)lo | ((unsigned)hi << 16);
    }
    uint4* dst = (uint4*)&outp[(size_t)(p0 + pr) * DCH + k0 + cg * 16];
    dst[0] = res.v[0];
    dst[1] = res.v[1];
}

// ---------------------------------------------------------------------------
// fp16 MFMA GEMM producing attention-friendly fp16 outputs:
//   q,k -> Yq/Yk [NH][NPOS][CH]   (p-major rows of 32 ch: direct MFMA frags)
//   v   -> Yv [DCH][NPOS]         (c-major: V^T A-frag rows)
// ---------------------------------------------------------------------------
__global__ __launch_bounds__(256) void qkv_gemm_f16(
        const f16_t* __restrict__ Wh,    // [THREE_D][DCH]
        const float* __restrict__ bias,  // [THREE_D]
        const f16_t* __restrict__ Xp,    // [NPOS][DCH]
        f16_t* __restrict__ Yq, f16_t* __restrict__ Yk, f16_t* __restrict__ Yv)
{
    __shared__ f16_t sha[128 * 32];  // [o_local][k] row-major, 8 KB
    __shared__ f16_t shb[128 * 32];  // [p_local][k] row-major, 8 KB
    const int tid  = threadIdx.x;
    const int lane = tid & 63;
    const int wave = tid >> 6;
    const int ot   = blockIdx.x;       // 0..8
    const int o0 = ot * 128;
    const int p0 = blockIdx.y * 128;
    const int wr = wave >> 1, wc = wave & 1;   // 2x2 wave grid

    f32x4 acc[4][4] = {};

    const int c0 = wave * 128 + lane;
    const int c1 = c0 + 64;
    const f16_t* ga0 = Wh + (size_t)(o0 + (c0 >> 2)) * DCH + (c0 & 3) * 8;
    const f16_t* ga1 = Wh + (size_t)(o0 + (c1 >> 2)) * DCH + (c1 & 3) * 8;
    const f16_t* gb0 = Xp + (size_t)(p0 + (c0 >> 2)) * DCH + (c0 & 3) * 8;
    const f16_t* gb1 = Xp + (size_t)(p0 + (c1 >> 2)) * DCH + (c1 & 3) * 8;
    f16_t* la0 = sha + (wave * 128) * 8;
    f16_t* la1 = sha + (wave * 128 + 64) * 8;
    f16_t* lb0 = shb + (wave * 128) * 8;
    f16_t* lb1 = shb + (wave * 128 + 64) * 8;

    const int mrow = lane & 15;
    const int kg8  = (lane >> 4) * 8;

    for (int kk = 0; kk < DCH; kk += 32) {
        GLD16(ga0 + kk, la0);
        GLD16(ga1 + kk, la1);
        GLD16(gb0 + kk, lb0);
        GLD16(gb1 + kk, lb1);
        __syncthreads();
        f16x8 af[4], bfr[4];
#pragma unroll
        for (int mi = 0; mi < 4; ++mi)
            af[mi] = *(const f16x8*)(sha + (wr * 64 + mi * 16 + mrow) * 32 + kg8);
#pragma unroll
        for (int ni = 0; ni < 4; ++ni)
            bfr[ni] = *(const f16x8*)(shb + (wc * 64 + ni * 16 + mrow) * 32 + kg8);
#pragma unroll
        for (int mi = 0; mi < 4; ++mi)
#pragma unroll
            for (int ni = 0; ni < 4; ++ni)
                acc[mi][ni] = __builtin_amdgcn_mfma_f32_16x16x32_f16(
                    af[mi], bfr[ni], acc[mi][ni], 0, 0, 0);
        __syncthreads();
    }

    // C/D layout: col = lane&15 (p), row = (lane>>4)*4 + r (o)
    const int col = lane & 15;
    const int rq4 = (lane >> 4) * 4;
    const int qkv = ot / 3;     // 0=q 1=k 2=v
    const int grp = ot % 3;     // 128-block within the qkv group

    if (qkv < 2) {
        f16_t* Yt = (qkv == 0) ? Yq : Yk;
#pragma unroll
        for (int mi = 0; mi < 4; ++mi) {
            const int h  = grp * 4 + wr * 2 + (mi >> 1);
            const int cb = (mi & 1) * 16 + rq4;               // c base; +r consecutive
            const int ob = o0 + wr * 64 + mi * 16 + rq4;      // bias base
            const float b0 = bias[ob], b1 = bias[ob + 1];
            const float b2 = bias[ob + 2], b3 = bias[ob + 3];
#pragma unroll
            for (int ni = 0; ni < 4; ++ni) {
                const int p = p0 + wc * 64 + ni * 16 + col;
                union { uint2 u; f16_t h4[4]; } w;
                w.h4[0] = (f16_t)(acc[mi][ni][0] + b0);
                w.h4[1] = (f16_t)(acc[mi][ni][1] + b1);
                w.h4[2] = (f16_t)(acc[mi][ni][2] + b2);
                w.h4[3] = (f16_t)(acc[mi][ni][3] + b3);
                *(uint2*)(Yt + ((size_t)h * NPOS + p) * CH + cb) = w.u;
            }
        }
    } else {
#pragma unroll
        for (int mi = 0; mi < 4; ++mi) {
#pragma unroll
            for (int r = 0; r < 4; ++r) {
                const int cg = grp * 128 + wr * 64 + mi * 16 + rq4 + r;  // 0..383
                const float br = bias[768 + cg];
#pragma unroll
                for (int ni = 0; ni < 4; ++ni) {
                    const int p = p0 + wc * 64 + ni * 16 + col;
                    Yv[(size_t)cg * NPOS + p] = (f16_t)(acc[mi][ni][r] + br);
                }
            }
        }
    }
}

// ---------------------------------------------------------------------------
// MFMA axial attention, LDS-staged K/V (one pass of coalesced global loads
// per block; all fragment re-reads from LDS), single __syncthreads after
// staging.  P round-trip stays per-wave (wave fence, no barrier).
// XT16: residual in fp16 T-domain [p][DCH] (stage 2) vs fp32 [c][p] (stage 1).
// ---------------------------------------------------------------------------
template <int SEQ, bool XT16>
__global__ __launch_bounds__(256) void mfma_attn(
        const f16_t* __restrict__ Yq, const f16_t* __restrict__ Yk,
        const f16_t* __restrict__ Yv, const void* __restrict__ Xv_,
        float* __restrict__ R)
{
    constexpr int JT  = SEQ / 16;    // j-tiles
    constexpr int NIT = SEQ / 64;    // i-tiles per wave
    constexpr int PST = SEQ + 8;     // padded P row stride (fp16 units)
    constexpr int VST = SEQ + 8;     // padded V row stride
    __shared__ f16_t Ks[SEQ * CH];       // [pos][ch] — linear copy of K slice
    __shared__ f16_t Vs[CH * VST];       // [ch][pos] — padded V^T slice
    __shared__ f16_t pb[4][16 * PST];
    const int tid  = threadIdx.x;
    const int lane = tid & 63;
    const int wave = tid >> 6;
    const int col = lane & 15, quad = lane >> 4;
    const int h = blockIdx.x % NH;
    const size_t pbase = (size_t)(blockIdx.x / NH) * SEQ;

    const f16_t* qg = Yq + ((size_t)h * NPOS + pbase) * CH;
    const f16_t* kg = Yk + ((size_t)h * NPOS + pbase) * CH;
    const f16_t* vg = Yv + (size_t)h * CH * NPOS + pbase;
    f16_t* mypb = pb[wave];

    // ---- stage K (async, linear). Global source MUST carry the lane term;
    //      LDS dest is wave-uniform base (+lane*16B by HW). ----
#pragma unroll
    for (int i = 0; i < SEQ / 64; ++i) {
        const int off = (wave * (SEQ / 64) + i) * 512;  // f16 units
        GLD16(kg + off + lane * 8, Ks + off);
    }
    // ---- stage V^T (coalesced float4, padded rows) ----
    {
        constexpr int CPR = SEQ / 8;        // 16B chunks per row
        const int vch = tid % CPR;
        const int vr0 = tid / CPR;          // rows per pass = 256/CPR
#pragma unroll
        for (int r = vr0; r < CH; r += 256 / CPR)
            *(float4*)(Vs + r * VST + vch * 8) =
                *(const float4*)(vg + (size_t)r * NPOS + vch * 8);
    }
    __syncthreads();   // drains vmcnt (K) + lgkm (V) -> LDS visible to all waves

    for (int it = 0; it < NIT; ++it) {
        const int i0 = (wave * NIT + it) * 16;
        const f16x8 qf = *(const f16x8*)(qg + (size_t)(i0 + col) * CH + quad * 8);
        f32x4 st[JT];
#pragma unroll
        for (int mt = 0; mt < JT; ++mt) {
            f16x8 kf = *(const f16x8*)(Ks + (mt * 16 + col) * CH + quad * 8);
            st[mt] = __builtin_amdgcn_mfma_f32_16x16x32_f16(kf, qf, (f32x4){0.f, 0.f, 0.f, 0.f}, 0, 0, 0);
        }
        float sum = 0.f;
#pragma unroll
        for (int mt = 0; mt < JT; ++mt)
#pragma unroll
            for (int r = 0; r < 4; ++r) {
                st[mt][r] = __expf(st[mt][r]);
                sum += st[mt][r];
            }
        sum += __shfl_xor(sum, 16, 64);
        sum += __shfl_xor(sum, 32, 64);
        const float inv = 1.f / sum;
#pragma unroll
        for (int mt = 0; mt < JT; ++mt) {
            union { uint2 u; f16_t h4[4]; } w;
            w.h4[0] = (f16_t)(st[mt][0] * inv);
            w.h4[1] = (f16_t)(st[mt][1] * inv);
            w.h4[2] = (f16_t)(st[mt][2] * inv);
            w.h4[3] = (f16_t)(st[mt][3] * inv);
            *(uint2*)(mypb + col * PST + mt * 16 + quad * 4) = w.u;
        }
        WAVE_LDS_FENCE();   // per-wave pb: wave-local drain suffices

        // PV: 2 accumulation chains per output row-pair to break MFMA latency
        f32x4 o0a = {0.f, 0.f, 0.f, 0.f}, o0b = {0.f, 0.f, 0.f, 0.f};
        f32x4 o1a = {0.f, 0.f, 0.f, 0.f}, o1b = {0.f, 0.f, 0.f, 0.f};
#pragma unroll
        for (int ks = 0; ks < SEQ / 32; ks += 2) {
            f16x8 pf0 = *(const f16x8*)(mypb + col * PST + ks * 32 + quad * 8);
            f16x8 pf1 = *(const f16x8*)(mypb + col * PST + (ks + 1) * 32 + quad * 8);
            f16x8 va0 = *(const f16x8*)(Vs + col * VST + ks * 32 + quad * 8);
            f16x8 va1 = *(const f16x8*)(Vs + col * VST + (ks + 1) * 32 + quad * 8);
            f16x8 vb0 = *(const f16x8*)(Vs + (16 + col) * VST + ks * 32 + quad * 8);
            f16x8 vb1 = *(const f16x8*)(Vs + (16 + col) * VST + (ks + 1) * 32 + quad * 8);
            o0a = __builtin_amdgcn_mfma_f32_16x16x32_f16(va0, pf0, o0a, 0, 0, 0);
            o0b = __builtin_amdgcn_mfma_f32_16x16x32_f16(va1, pf1, o0b, 0, 0, 0);
            o1a = __builtin_amdgcn_mfma_f32_16x16x32_f16(vb0, pf0, o1a, 0, 0, 0);
            o1b = __builtin_amdgcn_mfma_f32_16x16x32_f16(vb1, pf1, o1b, 0, 0, 0);
        }
        const f32x4 ot0 = o0a + o0b;
        const f32x4 ot1 = o1a + o1b;

        const size_t pos = pbase + i0 + col;
        if constexpr (XT16) {
            const f16_t* Xh = (const f16_t*)Xv_;
            const f16x4 xa = *(const f16x4*)(Xh + pos * DCH + h * CH + quad * 4);
            const f16x4 xb = *(const f16x4*)(Xh + pos * DCH + h * CH + 16 + quad * 4);
#pragma unroll
            for (int r = 0; r < 4; ++r) {
                R[(size_t)(h * CH + quad * 4 + r) * NPOS + pos]      = (float)xa[r] + ot0[r];
                R[(size_t)(h * CH + 16 + quad * 4 + r) * NPOS + pos] = (float)xb[r] + ot1[r];
            }
        } else {
            const float* Xf = (const float*)Xv_;
#pragma unroll
            for (int r = 0; r < 4; ++r) {
                const size_t c0r = (size_t)(h * CH + quad * 4 + r) * NPOS + pos;
                const size_t c1r = (size_t)(h * CH + 16 + quad * 4 + r) * NPOS + pos;
                R[c0r] = Xf[c0r] + ot0[r];
                R[c1r] = Xf[c1r] + ot1[r];
            }
        }
    }
}

// ---------------------------------------------------------------------------
// LN stats: mu[p], rs[p] over the 384 channels of A[d][p].
// ---------------------------------------------------------------------------
__global__ __launch_bounds__(256) void ln_stats(const float* __restrict__ A,
                                                float* __restrict__ mu,
                                                float* __restrict__ rs) {
    __shared__ float ssum[4][64], ssq[4][64];
    const int i = threadIdx.x & 63;
    const int g = threadIdx.x >> 6;
    const int p = blockIdx.x * 64 + i;
    float sum = 0.f, sq = 0.f;
    const float* ap = A + (size_t)(g * 96) * NPOS + p;
#pragma unroll 4
    for (int d = 0; d < 96; ++d) {
        float v = ap[(size_t)d * NPOS];
        sum += v;
        sq += v * v;
    }
    ssum[g][i] = sum;
    ssq[g][i] = sq;
    __syncthreads();
    if (g == 0) {
        float s = ssum[0][i] + ssum[1][i] + ssum[2][i] + ssum[3][i];
        float q = ssq[0][i] + ssq[1][i] + ssq[2][i] + ssq[3][i];
        float m = s * (1.f / DCH);
        float var = q * (1.f / DCH) - m * m;
        mu[p] = m;
        rs[p] = rsqrtf(var + 1e-5f);
    }
}

// ---------------------------------------------------------------------------
// Fused LN-apply + transpose + fp16: A fp32 [d][s*LL+l] -> Xp fp16
// [(l*SS+s)][d].
// ---------------------------------------------------------------------------
__global__ __launch_bounds__(256) void norm_xT(
        const float* __restrict__ A, const float* __restrict__ mu,
        const float* __restrict__ rs, const float* __restrict__ w,
        const float* __restrict__ b, f16_t* __restrict__ Xp) {
    __shared__ float tile[64][65];
    const int l0 = (blockIdx.x & 3) * 64;          // LL/64 = 4
    const int s  = (blockIdx.x >> 2) & (SS - 1);   // 128
    const int k0 = (blockIdx.x >> 9) * 64;         // DCH/64 = 6
    const int tx = threadIdx.x & 63, ty = threadIdx.x >> 6;  // ty 0..3
    const int pos0 = s * LL + l0;
#pragma unroll
    for (int i = 0; i < 16; ++i) {
        const int d = k0 + ty * 16 + i;
        float v = A[(size_t)d * NPOS + pos0 + tx];
        tile[ty * 16 + i][tx] = (v - mu[pos0 + tx]) * rs[pos0 + tx] * w[d] + b[d];
    }
    __syncthreads();
    const int pr = threadIdx.x >> 2;   // l-offset 0..63
    const int cg = threadIdx.x & 3;    // 16-d group
    union { uint4 v[2]; unsigned int u[8]; } res;
#pragma unroll
    for (int j = 0; j < 8; ++j) {
        unsigned short lo = __builtin_bit_cast(unsigned short, (f16_t)tile[cg * 16 + 2 * j][pr]);
        unsigned short hi = __builtin_bit_cast(unsigned short, (f16_t)tile[cg * 16 + 2 * j + 1][pr]);
        res.u[j] = (unsigned)lo | ((unsigned)hi << 16);
    }
    uint4* dst = (uint4*)&Xp[(size_t)((l0 + pr) * SS + s) * DCH + k0 + cg * 16];
    dst[0] = res.v[0];
    dst[1] = res.v[1];
}

// ---------------------------------------------------------------------------
// Final: normalize + per-channel transpose back to original domain.
// ---------------------------------------------------------------------------
__global__ __launch_bounds__(256) void norm_transpose(
        const float* __restrict__ in, const float* __restrict__ mu,
        const float* __restrict__ rs, const float* __restrict__ w,
        const float* __restrict__ b, float* __restrict__ out, int Rr, int Cc) {
    __shared__ float tile[32][33];
    const int ntc = Cc >> 5, ntr = Rr >> 5;
    int tc = blockIdx.x % ntc;
    int tr = (blockIdx.x / ntc) % ntr;
    int d = blockIdx.x / (ntc * ntr);
    int tx = threadIdx.x & 31, ty = threadIdx.x >> 5;  // ty 0..7
    const float* ip = in + (size_t)d * Rr * Cc;
    float* op = out + (size_t)d * Rr * Cc;
    const float wd = w[d], bd = b[d];
#pragma unroll
    for (int i = 0; i < 32; i += 8) {
        const int r = tr * 32 + ty + i;
        const int c = tc * 32 + tx;
        const int pos = r * Cc + c;
        float v = ip[(size_t)r * Cc + c];
        tile[ty + i][tx] = (v - mu[pos]) * rs[pos] * wd + bd;
    }
    __syncthreads();
#pragma unroll
    for (int i = 0; i < 32; i += 8)
        op[(size_t)(tc * 32 + ty + i) * Rr + tr * 32 + tx] = tile[tx][ty + i];
}

extern "C" void kernel_launch(void* const* d_in, const int* in_sizes, int n_in,
                              void* d_out, int out_size, void* d_ws, size_t ws_size,
                              hipStream_t stream) {
    const float* x     = (const float*)d_in[0];
    const float* row_w = (const float*)d_in[1];
    const float* row_b = (const float*)d_in[2];
    const float* col_w = (const float*)d_in[3];
    const float* col_b = (const float*)d_in[4];
    const float* ln1_w = (const float*)d_in[5];
    const float* ln1_b = (const float*)d_in[6];
    const float* ln2_w = (const float*)d_in[7];
    const float* ln2_b = (const float*)d_in[8];
    float* out = (float*)d_out;

    char* ws = (char*)d_ws;
    const size_t ysz = (size_t)NH * NPOS * CH * 2;   // 25.2 MB (== DCH*NPOS*2)
    const size_t abytes = (size_t)DCH * NPOS * 4;    // 50.3 MB
    f16_t* Yq = (f16_t*)ws;
    f16_t* Yk = (f16_t*)(ws + ysz);
    f16_t* Yv = (f16_t*)(ws + 2 * ysz);
    float* A  = (float*)(ws + 3 * ysz);
    f16_t* Xp = (f16_t*)(ws + 3 * ysz + abytes);
    f16_t* Wh = (f16_t*)(ws + 3 * ysz + abytes + ysz);
    float* MU = (float*)(ws + 3 * ysz + abytes + ysz + (1 << 21));
    float* RS = MU + NPOS;

    dim3 ggrid(THREE_D / 128, NPOS / 128);   // x = o-tile (9), y = p-tile (256)
    const int wn4 = THREE_D * DCH / 4;
    dim3 cgrid(NPOS / 64, DCH / 64);

    // ---- stage 1: row attention (attend over L within each row s) ----
    conv_w<<<(wn4 + 255) / 256, 256, 0, stream>>>(row_w, Wh, wn4);
    conv_xT<<<cgrid, 256, 0, stream>>>(x, Xp);
    qkv_gemm_f16<<<ggrid, 256, 0, stream>>>(Wh, row_b, Xp, Yq, Yk, Yv);
    mfma_attn<LL, false><<<NH * SS, 256, 0, stream>>>(Yq, Yk, Yv, x, A);  // A = x + row_out
    ln_stats<<<NPOS / 64, 256, 0, stream>>>(A, MU, RS);
    norm_xT<<<(DCH / 64) * SS * (LL / 64), 256, 0, stream>>>(A, MU, RS, ln1_w, ln1_b, Xp);

    // ---- stage 2: column attention (attend over S within each column l) ----
    conv_w<<<(wn4 + 255) / 256, 256, 0, stream>>>(col_w, Wh, wn4);
    qkv_gemm_f16<<<ggrid, 256, 0, stream>>>(Wh, col_b, Xp, Yq, Yk, Yv);
    mfma_attn<SS, true><<<NH * LL, 256, 0, stream>>>(Yq, Yk, Yv, Xp, A);  // A = out1 + col_out
    ln_stats<<<NPOS / 64, 256, 0, stream>>>(A, MU, RS);
    norm_transpose<<<DCH * (LL / 32) * (SS / 32), 256, 0, stream>>>(
        A, MU, RS, ln2_w, ln2_b, out, LL, SS);
}